// Round 6
// baseline (581.787 us; speedup 1.0000x reference)
//
#include <hip/hip_runtime.h>

// ---------------------------------------------------------------------------
// Qwen3-style attention block on MI355X (gfx950), bf16 MFMA pipeline.
// B=2, S=1024, HID=4096, H=32, KV=8, D=128.
// Stages: cvt(h,Wq,Wk,Wv) -> QKV GEMM (+Wo-cvt tail) -> RMSNorm+RoPE
//         -> flash attn -> out GEMM.
// GEMM core (v6): m201 8-phase skeleton + ISSUE-AHEAD-1 register fragments
// with COUNTED lgkmcnt (LDS analog of T4): each phase issues the next
// phase's ds_reads; waits are counted so drains hide under MFMA clusters.
// Quad order q00,q01,q11,q10; b0 double-buffered (compile-time via 2x
// K-loop unroll); vmcnt(LA+2) at phase-4 start (tile kt+1 fully landed
// before the post-barrier a0/b0 prefetch reads).
// ---------------------------------------------------------------------------

typedef __attribute__((ext_vector_type(8))) short s8v;            // 8 bf16 (4 VGPR)
typedef __attribute__((ext_vector_type(4))) float f4v;
typedef __attribute__((ext_vector_type(8))) unsigned short u8v;
typedef __attribute__((ext_vector_type(4))) float float4v;
typedef __attribute__((ext_vector_type(2))) float float2v;
typedef unsigned short us;

#define SB() __builtin_amdgcn_sched_barrier(0)

__device__ __forceinline__ void BARRIER() {
  asm volatile("" ::: "memory");
  __builtin_amdgcn_s_barrier();
  asm volatile("" ::: "memory");
}

__device__ __forceinline__ us f2b(float f) {
  unsigned u = __builtin_bit_cast(unsigned, f);
  u += 0x7fffu + ((u >> 16) & 1u);            // round-to-nearest-even
  return (us)(u >> 16);
}
__device__ __forceinline__ float b2f(us h) {
  return __builtin_bit_cast(float, (unsigned)h << 16);
}

__device__ __forceinline__ void gload16(const void* g, void* l) {
  __builtin_amdgcn_global_load_lds(
      (const __attribute__((address_space(1))) unsigned int*)g,
      (__attribute__((address_space(3))) unsigned int*)l, 16, 0, 0);
}

// ---------------------------------------------------------------------------
// Fused f32 -> bf16 convert: hidden|Wq|Wk|Wv, contiguous bf16 destination.
// ---------------------------------------------------------------------------
__global__ __launch_bounds__(256) void cvt_all_k(const float* __restrict__ h,
                                                 const float* __restrict__ wq,
                                                 const float* __restrict__ wk,
                                                 const float* __restrict__ wv,
                                                 us* __restrict__ dst) {
  long blk = blockIdx.x;
  const float* src;
  long off;
  if (blk < 4096)        { src = h;  off = 0; }
  else if (blk < 12288)  { src = wq; off = 4096; }
  else if (blk < 14336)  { src = wk; off = 12288; }
  else                   { src = wv; off = 14336; }
  long i = (blk - off) * 2048 + (long)threadIdx.x * 8;
  long o = blk * 2048 + (long)threadIdx.x * 8;
  float4v a = *(const float4v*)(src + i);
  float4v b = *(const float4v*)(src + i + 4);
  u8v v;
  v[0] = f2b(a[0]); v[1] = f2b(a[1]); v[2] = f2b(a[2]); v[3] = f2b(a[3]);
  v[4] = f2b(b[0]); v[5] = f2b(b[1]); v[6] = f2b(b[2]); v[7] = f2b(b[3]);
  *(u8v*)(dst + o) = v;
}

// ---------------------------------------------------------------------------
// 8-phase bf16 GEMM with issue-ahead-1 counted-lgkm: C = A[M,K] * W[N,K]^T
// Tile = (2*AH) x 256, BK=64, 512 threads (8 waves, 2M x 4N).
// LDS: A[2][2][AH*64] + B[2][2][128*64].
// Per K-tile: ph1{issue b1 | stage B0(kt+1) | lgkm(4) | q00=a0*b0}
//             ph2{issue a1 | stage A0(kt+2) | lgkm(2FR) | q01=a0*b1}
//             ph3{          stage B1(kt+2) | lgkm(0)   | q11=a1*b1}
//             ph4{vmcnt(LA+2) | stage A1(kt+2) | barrier |
//                 issue a0',b0'(kt+1) | lgkm(2FR+4) | q10=a1*b0}
// b0 ping-pongs between two register sets by kt parity (loop unrolled x2).
// ---------------------------------------------------------------------------
template <int AH, bool F32OUT, bool CVTTAIL>
__global__ __launch_bounds__(512, 2) void gemm8p(const us* __restrict__ A,
                                                 const us* __restrict__ W,
                                                 void* __restrict__ Cv,
                                                 int K, int nkt, int ldc,
                                                 int cm, int cn, int ncn,
                                                 int nGemm,
                                                 const float* __restrict__ csrc,
                                                 us* __restrict__ cdst) {
  if constexpr (CVTTAIL) {
    if ((int)blockIdx.x >= nGemm) {
      long c = (long)((int)blockIdx.x - nGemm) * 512 + threadIdx.x;
      for (; c < 2097152; c += 64 * 512) {      // 16,777,216 elems / 8
        long i = c * 8;
        float4v x = *(const float4v*)(csrc + i);
        float4v y = *(const float4v*)(csrc + i + 4);
        u8v v;
        v[0] = f2b(x[0]); v[1] = f2b(x[1]); v[2] = f2b(x[2]); v[3] = f2b(x[3]);
        v[4] = f2b(y[0]); v[5] = f2b(y[1]); v[6] = f2b(y[2]); v[7] = f2b(y[3]);
        *(u8v*)(cdst + i) = v;
      }
      return;
    }
  }

  constexpr int FR = AH / 32;          // A row-frags per wave per half
  constexpr int LA = AH / 64;          // gload_lds per thread per A-half

  __shared__ __align__(16) us Ah[2][2][AH * 64];
  __shared__ __align__(16) us Bh[2][2][128 * 64];
  const int tid = threadIdx.x, lane = tid & 63, w = tid >> 6;
  const int wr = w >> 2, wc = w & 3;
  const int lr = lane & 15, lg = lane >> 4;

  // 2D XCD chunking: xcd = bid&7 owns a cm x cn tile chunk, M-fastest inside.
  const int xcd = (int)blockIdx.x & 7;
  const int i2 = (int)blockIdx.x >> 3;
  const int im = i2 % cm, itn = i2 / cm;
  const long m0 = (long)((xcd / ncn) * cm + im) * (2 * AH);
  const long n0 = (long)((xcd % ncn) * cn + itn) * 256;

  // staging geometry: thread covers 16B chunk(s) l*512+tid of a half-tile
  const int rA0 = tid >> 3;                        // row for chunk l=0
  const int sc0 = ((tid & 7) ^ (rA0 & 7)) << 3;    // inverse-swizzled src col

#define STGH(dst, src, LOADS)                                           \
  do {                                                                  \
    const us* _s = (src);                                               \
    us* _d = (dst);                                                     \
    _Pragma("unroll") for (int l = 0; l < (LOADS); ++l)                 \
      gload16(_s + (long)(rA0 + l * 64) * K + sc0, _d + (l * 512 + tid) * 8); \
  } while (0)

  const us* Asrc = A + m0 * K;     // half h at + h*AH*K, K-tile kt at + kt*64
  const us* Bsrc = W + n0 * K;
  const long hKA = (long)AH * K;
  const long hKB = (long)128 * K;

  // fragment read offsets (elements; row*64 + swizzled-chunk*8)
  const int ra = wr * (AH / 2) + lr, rb = wc * 32 + lr;
  const int offA0 = ra * 64 + ((lg ^ (ra & 7)) << 3);
  const int offA1 = ra * 64 + (((4 + lg) ^ (ra & 7)) << 3);
  const int offB0 = rb * 64 + ((lg ^ (rb & 7)) << 3);
  const int offB1 = rb * 64 + (((4 + lg) ^ (rb & 7)) << 3);

  f4v acc[2 * FR][4];
#pragma unroll
  for (int i = 0; i < 2 * FR; ++i)
#pragma unroll
    for (int j = 0; j < 4; ++j) acc[i][j] = (f4v){0.f, 0.f, 0.f, 0.f};

  const int nk = nkt;

  s8v a0[FR][2], a1[FR][2], b0A[2][2], b0B[2][2], b1[2][2];

#define RD_A(AA, D, H)                                                  \
  _Pragma("unroll") for (int f = 0; f < FR; ++f) {                      \
    AA[f][0] = *(const s8v*)(&Ah[D][H][offA0 + f * 1024]);              \
    AA[f][1] = *(const s8v*)(&Ah[D][H][offA1 + f * 1024]);              \
  }
#define RD_B(BB, D, H)                                                  \
  _Pragma("unroll") for (int g = 0; g < 2; ++g) {                       \
    BB[g][0] = *(const s8v*)(&Bh[D][H][offB0 + g * 1024]);              \
    BB[g][1] = *(const s8v*)(&Bh[D][H][offB1 + g * 1024]);              \
  }
#define QUAD(AA, BB, QM, QN)                                            \
  __builtin_amdgcn_s_setprio(1);                                        \
  _Pragma("unroll") for (int f = 0; f < FR; ++f)                        \
  _Pragma("unroll") for (int g = 0; g < 2; ++g) {                       \
    f4v t = acc[QM * FR + f][QN * 2 + g];                               \
    t = __builtin_amdgcn_mfma_f32_16x16x32_bf16(AA[f][0], BB[g][0], t, 0, 0, 0); \
    t = __builtin_amdgcn_mfma_f32_16x16x32_bf16(AA[f][1], BB[g][1], t, 0, 0, 0); \
    acc[QM * FR + f][QN * 2 + g] = t;                                   \
  }                                                                     \
  __builtin_amdgcn_s_setprio(0);
#define LGKMW(N) asm volatile("s_waitcnt lgkmcnt(%0)" :: "i"(N) : "memory")
#define VMCNTW(N) asm volatile("s_waitcnt vmcnt(%0)" :: "i"(N) : "memory")

  // prologue: tile0 {A0,B0,B1,A1} + tile1 {A0,B1,A1}; wait tile0; issue a0,b0
  STGH(Ah[0][0], Asrc, LA);
  STGH(Bh[0][0], Bsrc, 2);
  STGH(Bh[0][1], Bsrc + hKB, 2);
  STGH(Ah[0][1], Asrc + hKA, LA);
  STGH(Ah[1][0], Asrc + 64, LA);
  STGH(Bh[1][1], Bsrc + hKB + 64, 2);
  STGH(Ah[1][1], Asrc + hKA + 64, LA);
  VMCNTW(2 * LA + 2);                  // tile0 landed; tile1 {A0,B1,A1} in flight
  BARRIER();
  RD_A(a0, 0, 0);                      // a0(0)
  RD_B(b0A, 0, 0);                     // b0(0) -> set A

#define TILE(KT, D, B0CUR, B0NXT)                                       \
  do {                                                                  \
    const int kt = (KT);                                                \
    const long kb2 = (long)(kt + 2) * 64;                               \
    const bool p1 = (kt + 1 < nk), p2 = (kt + 2 < nk);                  \
    /* ---- ph1: q00 = a0*b0 ---- */                                    \
    RD_B(b1, D, 1);                                                     \
    if (p1) STGH(Bh[(D) ^ 1][0], Bsrc + (long)(kt + 1) * 64, 2);        \
    BARRIER();                                                          \
    LGKMW(4); SB();                                                     \
    QUAD(a0, B0CUR, 0, 0)                                               \
    SB(); BARRIER();                                                    \
    /* ---- ph2: q01 = a0*b1 ---- */                                    \
    RD_A(a1, D, 1);                                                     \
    if (p2) STGH(Ah[D][0], Asrc + kb2, LA);                             \
    BARRIER();                                                          \
    LGKMW(2 * FR); SB();                                                \
    QUAD(a0, b1, 0, 1)                                                  \
    SB(); BARRIER();                                                    \
    /* ---- ph3: q11 = a1*b1 ---- */                                    \
    if (p2) STGH(Bh[D][1], Bsrc + hKB + kb2, 2);                        \
    BARRIER();                                                          \
    LGKMW(0); SB();                                                     \
    QUAD(a1, b1, 1, 1)                                                  \
    SB(); BARRIER();                                                    \
    /* ---- ph4: q10 = a1*b0; prefetch a0,b0 for kt+1 ---- */           \
    if (p2)      { VMCNTW(LA + 2); }                                    \
    else         { VMCNTW(0); }                                         \
    if (p2) STGH(Ah[D][1], Asrc + hKA + kb2, LA);                       \
    BARRIER();                                                          \
    if (p1) {                                                           \
      RD_A(a0, (D) ^ 1, 0);                                             \
      RD_B(B0NXT, (D) ^ 1, 0);                                          \
      LGKMW(2 * FR + 4);                                                \
    } else {                                                            \
      LGKMW(0);                                                         \
    }                                                                   \
    SB();                                                               \
    QUAD(a1, B0CUR, 1, 0)                                               \
    SB(); BARRIER();                                                    \
  } while (0)

  for (int kt2 = 0; kt2 < nk; kt2 += 2) {
    TILE(kt2, 0, b0A, b0B);
    TILE(kt2 + 1, 1, b0B, b0A);
  }

  // ---- epilogue ----
#pragma unroll
  for (int qm = 0; qm < 2; ++qm)
#pragma unroll
    for (int f = 0; f < FR; ++f) {
      long row = m0 + qm * AH + wr * (AH / 2) + f * 16 + lg * 4;
#pragma unroll
      for (int qn = 0; qn < 2; ++qn)
#pragma unroll
        for (int g = 0; g < 2; ++g) {
          long col = n0 + qn * 128 + wc * 32 + g * 16 + lr;
          f4v v = acc[qm * FR + f][qn * 2 + g];
          if constexpr (F32OUT) {
            float* C = (float*)Cv;
#pragma unroll
            for (int r = 0; r < 4; ++r) C[(row + r) * ldc + col] = v[r];
          } else {
            us* C = (us*)Cv;
#pragma unroll
            for (int r = 0; r < 4; ++r) C[(row + r) * ldc + col] = f2b(v[r]);
          }
        }
    }
#undef STGH
#undef RD_A
#undef RD_B
#undef QUAD
#undef TILE
#undef LGKMW
#undef VMCNTW
}

// ---------------------------------------------------------------------------
// Per-head RMSNorm (D=128) + RoPE, in-place, vectorized (us2 / float2).
// ---------------------------------------------------------------------------
__global__ __launch_bounds__(256) void rms_rope_k(us* __restrict__ qkv,
                                                  const float* __restrict__ fc,
                                                  const float* __restrict__ qw,
                                                  const float* __restrict__ kw) {
  int idx = blockIdx.x * 4 + (threadIdx.x >> 6);
  int lane = threadIdx.x & 63;
  int head = idx % 40;                 // 0..31 = Q heads, 32..39 = K heads
  int row = idx / 40;                  // b*1024 + s
  int s = row & 1023;
  us* p;
  const float* w;
  if (head < 32) { p = qkv + (long)row * 6144 + head * 128; w = qw; }
  else           { p = qkv + (long)row * 6144 + 4096 + (head - 32) * 128; w = kw; }

  unsigned v = ((const unsigned*)p)[lane];
  float x0 = b2f((us)(v & 0xffff)), x1 = b2f((us)(v >> 16));
  float ss = x0 * x0 + x1 * x1;
#pragma unroll
  for (int off = 32; off; off >>= 1) ss += __shfl_xor(ss, off);
  float r = rsqrtf(ss * (1.0f / 128.0f) + 1e-6f);
  float2v wv = ((const float2v*)w)[lane];
  float y0 = x0 * r * wv[0], y1 = x1 * r * wv[1];
  float py0 = __shfl(y0, lane ^ 32);
  float py1 = __shfl(y1, lane ^ 32);
  float2v cv = ((const float2v*)(fc + (long)s * 128))[lane];
  const float* sbase = (lane < 32) ? (fc + 2 * 1024 * 128) : (fc + 1024 * 128);
  float2v sv = ((const float2v*)(sbase + (long)s * 128))[lane];
  float e0 = y0 * cv[0] + py0 * sv[0];
  float e1 = y1 * cv[1] + py1 * sv[1];
  ((unsigned*)p)[lane] = (unsigned)f2b(e0) | ((unsigned)f2b(e1) << 16);
}

// ---------------------------------------------------------------------------
// Flash attention (no mask), GQA 4:1. Block = 4 waves = 64 q-rows; 64-key tiles.
// ---------------------------------------------------------------------------
__global__ __launch_bounds__(256) void attn_k(const us* __restrict__ qkv,
                                              us* __restrict__ ao) {
  __shared__ us Kt[64 * 128];   // [key][d], rows 256B, XOR-swizzled
  __shared__ us Vt[128 * 72];   // [d][key], padded rows (144B)
  __shared__ us Pl[4 * 1024];   // per-wave 16x64 P, XOR-swizzled

  const int bid = blockIdx.x;
  const int qt = bid & 15;
  const int h = (bid >> 4) & 31;
  const int b = bid >> 9;
  const int kvh = h >> 2;
  const int tid = threadIdx.x, lane = tid & 63, w = tid >> 6;
  const int lr = lane & 15, lg = lane >> 4;

  const us* Qb =
      qkv + (long)(b * 1024 + qt * 64 + w * 16 + lr) * 6144 + h * 128;
  s8v qf[4];
#pragma unroll
  for (int ks = 0; ks < 4; ++ks) qf[ks] = *(const s8v*)(Qb + ks * 32 + lg * 8);

  f4v o[8];
#pragma unroll
  for (int n = 0; n < 8; ++n) o[n] = (f4v){0.f, 0.f, 0.f, 0.f};
  float m[4], l[4];
#pragma unroll
  for (int r = 0; r < 4; ++r) { m[r] = -1e30f; l[r] = 0.f; }

  const float SL = 0.08838834764831845f * 1.4426950408889634f;  // D^-1/2 * log2e
  const long krow = (long)b * 1024 * 6144 + 4096 + kvh * 128;
  const long vrow = (long)b * 1024 * 6144 + 5120 + kvh * 128;

  for (int kt = 0; kt < 16; ++kt) {
    __syncthreads();
#pragma unroll
    for (int t = 0; t < 4; ++t) {
      int c = t * 256 + tid;
      int row = c >> 4;
      int sc = (c & 15) ^ (row & 7);
      gload16(qkv + krow + (long)(kt * 64 + row) * 6144 + sc * 8, &Kt[c * 8]);
    }
#pragma unroll
    for (int t = 0; t < 4; ++t) {
      int c = t * 256 + tid;
      int key = c & 63;
      int d0 = (c >> 6) * 8;
      s8v v = *(const s8v*)(qkv + vrow + (long)(kt * 64 + key) * 6144 + d0);
#pragma unroll
      for (int i = 0; i < 8; ++i) Vt[(d0 + i) * 72 + key] = (us)v[i];
    }
    __syncthreads();

    f4v sacc[4];
#pragma unroll
    for (int j = 0; j < 4; ++j) sacc[j] = (f4v){0.f, 0.f, 0.f, 0.f};
    __builtin_amdgcn_s_setprio(1);
#pragma unroll
    for (int ks = 0; ks < 4; ++ks) {
#pragma unroll
      for (int j = 0; j < 4; ++j) {
        int key = j * 16 + lr;
        s8v kf = *(const s8v*)&Kt[key * 128 + (((ks * 64 + lg * 16) ^ ((key & 7) << 4)) >> 1)];
        sacc[j] = __builtin_amdgcn_mfma_f32_16x16x32_bf16(qf[ks], kf, sacc[j], 0, 0, 0);
      }
    }
    __builtin_amdgcn_s_setprio(0);

    float sm[4];
#pragma unroll
    for (int r = 0; r < 4; ++r)
      sm[r] = fmaxf(fmaxf(sacc[0][r], sacc[1][r]), fmaxf(sacc[2][r], sacc[3][r]));
#pragma unroll
    for (int off = 1; off < 16; off <<= 1)
#pragma unroll
      for (int r = 0; r < 4; ++r) sm[r] = fmaxf(sm[r], __shfl_xor(sm[r], off));
    float alpha[4];
#pragma unroll
    for (int r = 0; r < 4; ++r) {
      float nm = fmaxf(m[r], sm[r] * SL);
      alpha[r] = exp2f(m[r] - nm);
      m[r] = nm;
      l[r] *= alpha[r];
    }
#pragma unroll
    for (int n = 0; n < 8; ++n)
#pragma unroll
      for (int r = 0; r < 4; ++r) o[n][r] *= alpha[r];

    us* pw = Pl + w * 1024;
#pragma unroll
    for (int j = 0; j < 4; ++j)
#pragma unroll
      for (int r = 0; r < 4; ++r) {
        float p = exp2f(sacc[j][r] * SL - m[r]);
        l[r] += p;
        int prow = lg * 4 + r, pcol = j * 16 + lr;
        pw[(prow * 128 + ((pcol * 2) ^ ((prow & 7) << 4))) >> 1] = f2b(p);
      }

    __builtin_amdgcn_s_setprio(1);
#pragma unroll
    for (int ks = 0; ks < 2; ++ks) {
      int bo = ks * 64 + lg * 16;
      s8v pf = *(const s8v*)&Pl[w * 1024 + ((lr * 128 + (bo ^ ((lr & 7) << 4))) >> 1)];
#pragma unroll
      for (int n = 0; n < 8; ++n) {
        s8v vf = *(const s8v*)&Vt[(n * 16 + lr) * 72 + ks * 32 + lg * 8];
        o[n] = __builtin_amdgcn_mfma_f32_16x16x32_bf16(pf, vf, o[n], 0, 0, 0);
      }
    }
    __builtin_amdgcn_s_setprio(0);
  }

#pragma unroll
  for (int off = 1; off < 16; off <<= 1)
#pragma unroll
    for (int r = 0; r < 4; ++r) l[r] += __shfl_xor(l[r], off);
  float inv[4];
#pragma unroll
  for (int r = 0; r < 4; ++r) inv[r] = 1.f / l[r];
  const long ob = (long)(b * 1024 + qt * 64 + w * 16) * 4096 + h * 128;
#pragma unroll
  for (int n = 0; n < 8; ++n)
#pragma unroll
    for (int r = 0; r < 4; ++r)
      ao[ob + (long)(lg * 4 + r) * 4096 + n * 16 + lr] = f2b(o[n][r] * inv[r]);
}

// ---------------------------------------------------------------------------
// Launch
// ---------------------------------------------------------------------------
extern "C" void kernel_launch(void* const* d_in, const int* in_sizes, int n_in,
                              void* d_out, int out_size, void* d_ws, size_t ws_size,
                              hipStream_t stream) {
  const float* hidden = (const float*)d_in[0];
  const float* fc     = (const float*)d_in[1];
  const float* Wq     = (const float*)d_in[2];
  const float* Wk     = (const float*)d_in[3];
  const float* Wv     = (const float*)d_in[4];
  const float* Wo     = (const float*)d_in[5];
  const float* qw     = (const float*)d_in[6];
  const float* kw     = (const float*)d_in[7];

  us* hb  = (us*)d_ws;                          // [2048][4096] bf16
  us* wb  = hb + (long)2048 * 4096;             // [10240][4096] bf16 (Wq|Wk|Wv|Wo)
  us* wbo = wb + (long)6144 * 4096;             // Wo bf16 [4096][4096]
  us* qkv = wbo + (long)4096 * 4096;            // [2048][6144] bf16
  us* ao  = qkv + (long)2048 * 6144;            // [2048][4096] bf16

  // convert hidden|Wq|Wk|Wv -> contiguous bf16 at hb (Wo converted in-gemm)
  cvt_all_k<<<16384, 256, 0, stream>>>(hidden, Wq, Wk, Wv, hb);

  // fused QKV projection (192 gemm blocks: 8M x 24N, XCD chunks 4Mx6N)
  // + Wo convert (64 tail blocks)
  gemm8p<128, false, true><<<256, 512, 0, stream>>>(
      hb, wb, qkv, 4096, 64, 6144, 4, 6, 4, 192, Wo, wbo);

  // per-head RMSNorm + RoPE in place
  rms_rope_k<<<20480, 256, 0, stream>>>(qkv, fc, qw, kw);

  // flash attention -> bf16 [2048][4096]
  attn_k<<<1024, 256, 0, stream>>>(qkv, ao);

  // output projection: BM=128, grid 256 (16M x 16N, XCD chunks 8Mx4N),
  // full-K, f32 -> d_out
  gemm8p<64, true, false><<<256, 512, 0, stream>>>(
      ao, wbo, d_out, 4096, 64, 4096, 8, 4, 4, 256, nullptr, nullptr);
}

// Round 7
// 379.035 us; speedup vs baseline: 1.5349x; 1.5349x over previous
//
#include <hip/hip_runtime.h>

// ---------------------------------------------------------------------------
// Qwen3-style attention block on MI355X (gfx950), bf16 MFMA pipeline.
// B=2, S=1024, HID=4096, H=32, KV=8, D=128.
// Stages: cvt(h,Wq,Wk,Wv) -> QKV GEMM (+Wo-cvt tail) -> RMSNorm+RoPE
//         -> flash attn -> out GEMM.
// GEMM core (v7): 8-phase skeleton + issue-ahead-1 register fragments with
// COUNTED lgkmcnt, SINGLE-buffered fragment sets (no spill @ lb(512,1)):
//   ph1: RD b1       | stage B0(kt+1) | lgkm(4)   | q00 = a0*b0
//   ph2: RD a1       | stage A0(kt+2) | lgkm(2FR) | q01 = a0*b1
//   ph3:             | stage B1(kt+2) | lgkm(0)   | q11 = a1*b1
//   ph4: vmcnt(LA+2) | stage A1(kt+2) | RD a0'(next) | lgkm(2FR) |
//        q10 = a1*b0 | RD b0'(next)
// a0' targets regs dead since ph2; b0' issued after q10's last b0 use and
// completes under the tile-boundary barrier (ph1' waits lgkm(4)).
// ---------------------------------------------------------------------------

typedef __attribute__((ext_vector_type(8))) short s8v;            // 8 bf16 (4 VGPR)
typedef __attribute__((ext_vector_type(4))) float f4v;
typedef __attribute__((ext_vector_type(8))) unsigned short u8v;
typedef __attribute__((ext_vector_type(4))) float float4v;
typedef __attribute__((ext_vector_type(2))) float float2v;
typedef unsigned short us;

#define SB() __builtin_amdgcn_sched_barrier(0)

__device__ __forceinline__ void BARRIER() {
  asm volatile("" ::: "memory");
  __builtin_amdgcn_s_barrier();
  asm volatile("" ::: "memory");
}

__device__ __forceinline__ us f2b(float f) {
  unsigned u = __builtin_bit_cast(unsigned, f);
  u += 0x7fffu + ((u >> 16) & 1u);            // round-to-nearest-even
  return (us)(u >> 16);
}
__device__ __forceinline__ float b2f(us h) {
  return __builtin_bit_cast(float, (unsigned)h << 16);
}

__device__ __forceinline__ void gload16(const void* g, void* l) {
  __builtin_amdgcn_global_load_lds(
      (const __attribute__((address_space(1))) unsigned int*)g,
      (__attribute__((address_space(3))) unsigned int*)l, 16, 0, 0);
}

// ---------------------------------------------------------------------------
// Fused f32 -> bf16 convert: hidden|Wq|Wk|Wv, contiguous bf16 destination.
// ---------------------------------------------------------------------------
__global__ __launch_bounds__(256) void cvt_all_k(const float* __restrict__ h,
                                                 const float* __restrict__ wq,
                                                 const float* __restrict__ wk,
                                                 const float* __restrict__ wv,
                                                 us* __restrict__ dst) {
  long blk = blockIdx.x;
  const float* src;
  long off;
  if (blk < 4096)        { src = h;  off = 0; }
  else if (blk < 12288)  { src = wq; off = 4096; }
  else if (blk < 14336)  { src = wk; off = 12288; }
  else                   { src = wv; off = 14336; }
  long i = (blk - off) * 2048 + (long)threadIdx.x * 8;
  long o = blk * 2048 + (long)threadIdx.x * 8;
  float4v a = *(const float4v*)(src + i);
  float4v b = *(const float4v*)(src + i + 4);
  u8v v;
  v[0] = f2b(a[0]); v[1] = f2b(a[1]); v[2] = f2b(a[2]); v[3] = f2b(a[3]);
  v[4] = f2b(b[0]); v[5] = f2b(b[1]); v[6] = f2b(b[2]); v[7] = f2b(b[3]);
  *(u8v*)(dst + o) = v;
}

// ---------------------------------------------------------------------------
// 8-phase bf16 GEMM, issue-ahead-1 counted-lgkm: C = A[M,K] * W[N,K]^T
// Tile = (2*AH) x 256, BK=64, 512 threads (8 waves, 2M x 4N).
// LDS: A[2][2][AH*64] + B[2][2][128*64]; 1 block/CU (LDS-limited).
// ---------------------------------------------------------------------------
template <int AH, bool F32OUT, bool CVTTAIL>
__global__ __launch_bounds__(512, 1) void gemm8p(const us* __restrict__ A,
                                                 const us* __restrict__ W,
                                                 void* __restrict__ Cv,
                                                 int K, int nkt, int ldc,
                                                 int cm, int cn, int ncn,
                                                 int nGemm,
                                                 const float* __restrict__ csrc,
                                                 us* __restrict__ cdst) {
  if constexpr (CVTTAIL) {
    if ((int)blockIdx.x >= nGemm) {
      long c = (long)((int)blockIdx.x - nGemm) * 512 + threadIdx.x;
      for (; c < 2097152; c += 64 * 512) {      // 16,777,216 elems / 8
        long i = c * 8;
        float4v x = *(const float4v*)(csrc + i);
        float4v y = *(const float4v*)(csrc + i + 4);
        u8v v;
        v[0] = f2b(x[0]); v[1] = f2b(x[1]); v[2] = f2b(x[2]); v[3] = f2b(x[3]);
        v[4] = f2b(y[0]); v[5] = f2b(y[1]); v[6] = f2b(y[2]); v[7] = f2b(y[3]);
        *(u8v*)(cdst + i) = v;
      }
      return;
    }
  }

  constexpr int FR = AH / 32;          // A row-frags per wave per half
  constexpr int LA = AH / 64;          // gload_lds per thread per A-half

  __shared__ __align__(16) us Ah[2][2][AH * 64];
  __shared__ __align__(16) us Bh[2][2][128 * 64];
  const int tid = threadIdx.x, lane = tid & 63, w = tid >> 6;
  const int wr = w >> 2, wc = w & 3;
  const int lr = lane & 15, lg = lane >> 4;

  // 2D XCD chunking: xcd = bid&7 owns a cm x cn tile chunk, M-fastest inside.
  const int xcd = (int)blockIdx.x & 7;
  const int i2 = (int)blockIdx.x >> 3;
  const int im = i2 % cm, itn = i2 / cm;
  const long m0 = (long)((xcd / ncn) * cm + im) * (2 * AH);
  const long n0 = (long)((xcd % ncn) * cn + itn) * 256;

  // staging geometry: thread covers 16B chunk(s) l*512+tid of a half-tile
  const int rA0 = tid >> 3;                        // row for chunk l=0
  const int sc0 = ((tid & 7) ^ (rA0 & 7)) << 3;    // inverse-swizzled src col

#define STGH(dst, src, LOADS)                                           \
  do {                                                                  \
    const us* _s = (src);                                               \
    us* _d = (dst);                                                     \
    _Pragma("unroll") for (int l = 0; l < (LOADS); ++l)                 \
      gload16(_s + (long)(rA0 + l * 64) * K + sc0, _d + (l * 512 + tid) * 8); \
  } while (0)

  const us* Asrc = A + m0 * K;     // half h at + h*AH*K, K-tile kt at + kt*64
  const us* Bsrc = W + n0 * K;
  const long hKA = (long)AH * K;
  const long hKB = (long)128 * K;

  // fragment read offsets (elements; row*64 + swizzled-chunk*8)
  const int ra = wr * (AH / 2) + lr, rb = wc * 32 + lr;
  const int offA0 = ra * 64 + ((lg ^ (ra & 7)) << 3);
  const int offA1 = ra * 64 + (((4 + lg) ^ (ra & 7)) << 3);
  const int offB0 = rb * 64 + ((lg ^ (rb & 7)) << 3);
  const int offB1 = rb * 64 + (((4 + lg) ^ (rb & 7)) << 3);

  f4v acc[2 * FR][4];
#pragma unroll
  for (int i = 0; i < 2 * FR; ++i)
#pragma unroll
    for (int j = 0; j < 4; ++j) acc[i][j] = (f4v){0.f, 0.f, 0.f, 0.f};

  const int nk = nkt;

  s8v a0[FR][2], a1[FR][2], b0[2][2], b1[2][2];

#define RD_A(AA, D, H)                                                  \
  _Pragma("unroll") for (int f = 0; f < FR; ++f) {                      \
    AA[f][0] = *(const s8v*)(&Ah[D][H][offA0 + f * 1024]);              \
    AA[f][1] = *(const s8v*)(&Ah[D][H][offA1 + f * 1024]);              \
  }
#define RD_B(BB, D, H)                                                  \
  _Pragma("unroll") for (int g = 0; g < 2; ++g) {                       \
    BB[g][0] = *(const s8v*)(&Bh[D][H][offB0 + g * 1024]);              \
    BB[g][1] = *(const s8v*)(&Bh[D][H][offB1 + g * 1024]);              \
  }
#define QUAD(AA, BB, QM, QN)                                            \
  __builtin_amdgcn_s_setprio(1);                                        \
  _Pragma("unroll") for (int f = 0; f < FR; ++f)                        \
  _Pragma("unroll") for (int g = 0; g < 2; ++g) {                       \
    f4v t = acc[QM * FR + f][QN * 2 + g];                               \
    t = __builtin_amdgcn_mfma_f32_16x16x32_bf16(AA[f][0], BB[g][0], t, 0, 0, 0); \
    t = __builtin_amdgcn_mfma_f32_16x16x32_bf16(AA[f][1], BB[g][1], t, 0, 0, 0); \
    acc[QM * FR + f][QN * 2 + g] = t;                                   \
  }                                                                     \
  __builtin_amdgcn_s_setprio(0);
#define LGKMW(N) asm volatile("s_waitcnt lgkmcnt(%0)" :: "i"(N) : "memory")
#define VMCNTW(N) asm volatile("s_waitcnt vmcnt(%0)" :: "i"(N) : "memory")

  // prologue: stage tile0 {A0,B0,B1,A1} + tile1 {A0,B1,A1}; B0(1) comes from
  // ph1(0), A1(2) from ph4(0). Wait keeps tile1's {A0,B1,A1} in flight.
  STGH(Ah[0][0], Asrc, LA);
  STGH(Bh[0][0], Bsrc, 2);
  STGH(Bh[0][1], Bsrc + hKB, 2);
  STGH(Ah[0][1], Asrc + hKA, LA);
  STGH(Ah[1][0], Asrc + 64, LA);
  STGH(Bh[1][1], Bsrc + hKB + 64, 2);
  STGH(Ah[1][1], Asrc + hKA + 64, LA);
  VMCNTW(2 * LA + 2);                  // tile0 landed
  BARRIER();
  RD_A(a0, 0, 0);                      // a0(0)
  RD_B(b0, 0, 0);                      // b0(0)

  for (int kt = 0; kt < nk; ++kt) {
    const int d = kt & 1;
    const long kb2 = (long)(kt + 2) * 64;
    const bool p1 = (kt + 1 < nk), p2 = (kt + 2 < nk);

    // ---- ph1: q00 = a0*b0; RD b1; stage B0(kt+1) ----
    RD_B(b1, d, 1);
    if (p1) STGH(Bh[d ^ 1][0], Bsrc + (long)(kt + 1) * 64, 2);
    BARRIER();
    LGKMW(4); SB();                    // a0,b0 ready; b1's 4 reads in flight
    QUAD(a0, b0, 0, 0)
    SB(); BARRIER();

    // ---- ph2: q01 = a0*b1; RD a1; stage A0(kt+2) ----
    RD_A(a1, d, 1);
    if (p2) STGH(Ah[d][0], Asrc + kb2, LA);
    BARRIER();
    LGKMW(2 * FR); SB();               // b1 ready; a1's 2FR reads in flight
    QUAD(a0, b1, 0, 1)
    SB(); BARRIER();

    // ---- ph3: q11 = a1*b1; stage B1(kt+2) ----
    if (p2) STGH(Bh[d][1], Bsrc + hKB + kb2, 2);
    BARRIER();
    LGKMW(0); SB();                    // a1 ready
    QUAD(a1, b1, 1, 1)
    SB(); BARRIER();

    // ---- ph4: q10 = a1*b0; vmcnt; stage A1(kt+2); prefetch a0',b0' ----
    if (p2)      { VMCNTW(LA + 2); }   // all of tile kt+1 landed
    else         { VMCNTW(0); }
    if (p2) STGH(Ah[d][1], Asrc + hKA + kb2, LA);
    BARRIER();
    if (p1) {
      RD_A(a0, d ^ 1, 0);              // a0 regs dead since ph2
      LGKMW(2 * FR);
    } else {
      LGKMW(0);
    }
    SB();
    QUAD(a1, b0, 1, 0)
    SB();
    if (p1) RD_B(b0, d ^ 1, 0);        // after q10's last b0 use
    BARRIER();
  }

  // ---- epilogue ----
#pragma unroll
  for (int qm = 0; qm < 2; ++qm)
#pragma unroll
    for (int f = 0; f < FR; ++f) {
      long row = m0 + qm * AH + wr * (AH / 2) + f * 16 + lg * 4;
#pragma unroll
      for (int qn = 0; qn < 2; ++qn)
#pragma unroll
        for (int g = 0; g < 2; ++g) {
          long col = n0 + qn * 128 + wc * 32 + g * 16 + lr;
          f4v v = acc[qm * FR + f][qn * 2 + g];
          if constexpr (F32OUT) {
            float* C = (float*)Cv;
#pragma unroll
            for (int r = 0; r < 4; ++r) C[(row + r) * ldc + col] = v[r];
          } else {
            us* C = (us*)Cv;
#pragma unroll
            for (int r = 0; r < 4; ++r) C[(row + r) * ldc + col] = f2b(v[r]);
          }
        }
    }
#undef STGH
#undef RD_A
#undef RD_B
#undef QUAD
#undef LGKMW
#undef VMCNTW
}

// ---------------------------------------------------------------------------
// Per-head RMSNorm (D=128) + RoPE, in-place, vectorized (us2 / float2).
// ---------------------------------------------------------------------------
__global__ __launch_bounds__(256) void rms_rope_k(us* __restrict__ qkv,
                                                  const float* __restrict__ fc,
                                                  const float* __restrict__ qw,
                                                  const float* __restrict__ kw) {
  int idx = blockIdx.x * 4 + (threadIdx.x >> 6);
  int lane = threadIdx.x & 63;
  int head = idx % 40;                 // 0..31 = Q heads, 32..39 = K heads
  int row = idx / 40;                  // b*1024 + s
  int s = row & 1023;
  us* p;
  const float* w;
  if (head < 32) { p = qkv + (long)row * 6144 + head * 128; w = qw; }
  else           { p = qkv + (long)row * 6144 + 4096 + (head - 32) * 128; w = kw; }

  unsigned v = ((const unsigned*)p)[lane];
  float x0 = b2f((us)(v & 0xffff)), x1 = b2f((us)(v >> 16));
  float ss = x0 * x0 + x1 * x1;
#pragma unroll
  for (int off = 32; off; off >>= 1) ss += __shfl_xor(ss, off);
  float r = rsqrtf(ss * (1.0f / 128.0f) + 1e-6f);
  float2v wv = ((const float2v*)w)[lane];
  float y0 = x0 * r * wv[0], y1 = x1 * r * wv[1];
  float py0 = __shfl(y0, lane ^ 32);
  float py1 = __shfl(y1, lane ^ 32);
  float2v cv = ((const float2v*)(fc + (long)s * 128))[lane];
  const float* sbase = (lane < 32) ? (fc + 2 * 1024 * 128) : (fc + 1024 * 128);
  float2v sv = ((const float2v*)(sbase + (long)s * 128))[lane];
  float e0 = y0 * cv[0] + py0 * sv[0];
  float e1 = y1 * cv[1] + py1 * sv[1];
  ((unsigned*)p)[lane] = (unsigned)f2b(e0) | ((unsigned)f2b(e1) << 16);
}

// ---------------------------------------------------------------------------
// Flash attention (no mask), GQA 4:1. Block = 4 waves = 64 q-rows; 64-key tiles.
// ---------------------------------------------------------------------------
__global__ __launch_bounds__(256) void attn_k(const us* __restrict__ qkv,
                                              us* __restrict__ ao) {
  __shared__ us Kt[64 * 128];   // [key][d], rows 256B, XOR-swizzled
  __shared__ us Vt[128 * 72];   // [d][key], padded rows (144B)
  __shared__ us Pl[4 * 1024];   // per-wave 16x64 P, XOR-swizzled

  const int bid = blockIdx.x;
  const int qt = bid & 15;
  const int h = (bid >> 4) & 31;
  const int b = bid >> 9;
  const int kvh = h >> 2;
  const int tid = threadIdx.x, lane = tid & 63, w = tid >> 6;
  const int lr = lane & 15, lg = lane >> 4;

  const us* Qb =
      qkv + (long)(b * 1024 + qt * 64 + w * 16 + lr) * 6144 + h * 128;
  s8v qf[4];
#pragma unroll
  for (int ks = 0; ks < 4; ++ks) qf[ks] = *(const s8v*)(Qb + ks * 32 + lg * 8);

  f4v o[8];
#pragma unroll
  for (int n = 0; n < 8; ++n) o[n] = (f4v){0.f, 0.f, 0.f, 0.f};
  float m[4], l[4];
#pragma unroll
  for (int r = 0; r < 4; ++r) { m[r] = -1e30f; l[r] = 0.f; }

  const float SL = 0.08838834764831845f * 1.4426950408889634f;  // D^-1/2 * log2e
  const long krow = (long)b * 1024 * 6144 + 4096 + kvh * 128;
  const long vrow = (long)b * 1024 * 6144 + 5120 + kvh * 128;

  for (int kt = 0; kt < 16; ++kt) {
    __syncthreads();
#pragma unroll
    for (int t = 0; t < 4; ++t) {
      int c = t * 256 + tid;
      int row = c >> 4;
      int sc = (c & 15) ^ (row & 7);
      gload16(qkv + krow + (long)(kt * 64 + row) * 6144 + sc * 8, &Kt[c * 8]);
    }
#pragma unroll
    for (int t = 0; t < 4; ++t) {
      int c = t * 256 + tid;
      int key = c & 63;
      int d0 = (c >> 6) * 8;
      s8v v = *(const s8v*)(qkv + vrow + (long)(kt * 64 + key) * 6144 + d0);
#pragma unroll
      for (int i = 0; i < 8; ++i) Vt[(d0 + i) * 72 + key] = (us)v[i];
    }
    __syncthreads();

    f4v sacc[4];
#pragma unroll
    for (int j = 0; j < 4; ++j) sacc[j] = (f4v){0.f, 0.f, 0.f, 0.f};
    __builtin_amdgcn_s_setprio(1);
#pragma unroll
    for (int ks = 0; ks < 4; ++ks) {
#pragma unroll
      for (int j = 0; j < 4; ++j) {
        int key = j * 16 + lr;
        s8v kf = *(const s8v*)&Kt[key * 128 + (((ks * 64 + lg * 16) ^ ((key & 7) << 4)) >> 1)];
        sacc[j] = __builtin_amdgcn_mfma_f32_16x16x32_bf16(qf[ks], kf, sacc[j], 0, 0, 0);
      }
    }
    __builtin_amdgcn_s_setprio(0);

    float sm[4];
#pragma unroll
    for (int r = 0; r < 4; ++r)
      sm[r] = fmaxf(fmaxf(sacc[0][r], sacc[1][r]), fmaxf(sacc[2][r], sacc[3][r]));
#pragma unroll
    for (int off = 1; off < 16; off <<= 1)
#pragma unroll
      for (int r = 0; r < 4; ++r) sm[r] = fmaxf(sm[r], __shfl_xor(sm[r], off));
    float alpha[4];
#pragma unroll
    for (int r = 0; r < 4; ++r) {
      float nm = fmaxf(m[r], sm[r] * SL);
      alpha[r] = exp2f(m[r] - nm);
      m[r] = nm;
      l[r] *= alpha[r];
    }
#pragma unroll
    for (int n = 0; n < 8; ++n)
#pragma unroll
      for (int r = 0; r < 4; ++r) o[n][r] *= alpha[r];

    us* pw = Pl + w * 1024;
#pragma unroll
    for (int j = 0; j < 4; ++j)
#pragma unroll
      for (int r = 0; r < 4; ++r) {
        float p = exp2f(sacc[j][r] * SL - m[r]);
        l[r] += p;
        int prow = lg * 4 + r, pcol = j * 16 + lr;
        pw[(prow * 128 + ((pcol * 2) ^ ((prow & 7) << 4))) >> 1] = f2b(p);
      }

    __builtin_amdgcn_s_setprio(1);
#pragma unroll
    for (int ks = 0; ks < 2; ++ks) {
      int bo = ks * 64 + lg * 16;
      s8v pf = *(const s8v*)&Pl[w * 1024 + ((lr * 128 + (bo ^ ((lr & 7) << 4))) >> 1)];
#pragma unroll
      for (int n = 0; n < 8; ++n) {
        s8v vf = *(const s8v*)&Vt[(n * 16 + lr) * 72 + ks * 32 + lg * 8];
        o[n] = __builtin_amdgcn_mfma_f32_16x16x32_bf16(pf, vf, o[n], 0, 0, 0);
      }
    }
    __builtin_amdgcn_s_setprio(0);
  }

#pragma unroll
  for (int off = 1; off < 16; off <<= 1)
#pragma unroll
    for (int r = 0; r < 4; ++r) l[r] += __shfl_xor(l[r], off);
  float inv[4];
#pragma unroll
  for (int r = 0; r < 4; ++r) inv[r] = 1.f / l[r];
  const long ob = (long)(b * 1024 + qt * 64 + w * 16) * 4096 + h * 128;
#pragma unroll
  for (int n = 0; n < 8; ++n)
#pragma unroll
    for (int r = 0; r < 4; ++r)
      ao[ob + (long)(lg * 4 + r) * 4096 + n * 16 + lr] = f2b(o[n][r] * inv[r]);
}

// ---------------------------------------------------------------------------
// Launch
// ---------------------------------------------------------------------------
extern "C" void kernel_launch(void* const* d_in, const int* in_sizes, int n_in,
                              void* d_out, int out_size, void* d_ws, size_t ws_size,
                              hipStream_t stream) {
  const float* hidden = (const float*)d_in[0];
  const float* fc     = (const float*)d_in[1];
  const float* Wq     = (const float*)d_in[2];
  const float* Wk     = (const float*)d_in[3];
  const float* Wv     = (const float*)d_in[4];
  const float* Wo     = (const float*)d_in[5];
  const float* qw     = (const float*)d_in[6];
  const float* kw     = (const float*)d_in[7];

  us* hb  = (us*)d_ws;                          // [2048][4096] bf16
  us* wb  = hb + (long)2048 * 4096;             // [10240][4096] bf16 (Wq|Wk|Wv|Wo)
  us* wbo = wb + (long)6144 * 4096;             // Wo bf16 [4096][4096]
  us* qkv = wbo + (long)4096 * 4096;            // [2048][6144] bf16
  us* ao  = qkv + (long)2048 * 6144;            // [2048][4096] bf16

  // convert hidden|Wq|Wk|Wv -> contiguous bf16 at hb (Wo converted in-gemm)
  cvt_all_k<<<16384, 256, 0, stream>>>(hidden, Wq, Wk, Wv, hb);

  // fused QKV projection (192 gemm blocks: 8M x 24N, XCD chunks 4Mx6N)
  // + Wo convert (64 tail blocks)
  gemm8p<128, false, true><<<256, 512, 0, stream>>>(
      hb, wb, qkv, 4096, 64, 6144, 4, 6, 4, 192, Wo, wbo);

  // per-head RMSNorm + RoPE in place
  rms_rope_k<<<20480, 256, 0, stream>>>(qkv, fc, qw, kw);

  // flash attention -> bf16 [2048][4096]
  attn_k<<<1024, 256, 0, stream>>>(qkv, ao);

  // output projection: BM=128, grid 256 (16M x 16N, XCD chunks 8Mx4N),
  // full-K, f32 -> d_out
  gemm8p<64, true, false><<<256, 512, 0, stream>>>(
      ao, wbo, d_out, 4096, 64, 4096, 8, 4, 4, 256, nullptr, nullptr);
}

// Round 8
// 337.505 us; speedup vs baseline: 1.7238x; 1.1231x over previous
//
#include <hip/hip_runtime.h>

// ---------------------------------------------------------------------------
// Qwen3-style attention block on MI355X (gfx950), bf16 MFMA pipeline.
// B=2, S=1024, HID=4096, H=32, KV=8, D=128.
// Stages: cvt(h,Wq,Wk,Wv) -> QKV GEMM (+Wo-cvt tail) -> K-RMSNorm+RoPE
//         -> flash attn (Q-RMSNorm+RoPE fused in prologue) -> out GEMM.
// GEMM core: round-5 structure (best measured: 345us total) — m201-style
// 8-phase, BN=256, BK=64, 8 waves (2Mx4N), templated A-half height AH,
// one half-tile staged per phase into the just-freed slot, counted
// vmcnt(2*LA+2) once per K-tile, setprio, chunk-XOR LDS swizzle, 2D XCD
// chunking. Delta vs R5: no sched_barrier after the MFMA cluster (m141).
// ---------------------------------------------------------------------------

typedef __attribute__((ext_vector_type(8))) short s8v;            // 8 bf16 (4 VGPR)
typedef __attribute__((ext_vector_type(4))) float f4v;
typedef __attribute__((ext_vector_type(8))) unsigned short u8v;
typedef __attribute__((ext_vector_type(4))) float float4v;
typedef __attribute__((ext_vector_type(2))) float float2v;
typedef unsigned short us;

#define SB() __builtin_amdgcn_sched_barrier(0)

__device__ __forceinline__ void BARRIER() {
  asm volatile("" ::: "memory");
  __builtin_amdgcn_s_barrier();
  asm volatile("" ::: "memory");
}

__device__ __forceinline__ us f2b(float f) {
  unsigned u = __builtin_bit_cast(unsigned, f);
  u += 0x7fffu + ((u >> 16) & 1u);            // round-to-nearest-even
  return (us)(u >> 16);
}
__device__ __forceinline__ float b2f(us h) {
  return __builtin_bit_cast(float, (unsigned)h << 16);
}

__device__ __forceinline__ void gload16(const void* g, void* l) {
  __builtin_amdgcn_global_load_lds(
      (const __attribute__((address_space(1))) unsigned int*)g,
      (__attribute__((address_space(3))) unsigned int*)l, 16, 0, 0);
}

// ---------------------------------------------------------------------------
// Fused f32 -> bf16 convert: hidden|Wq|Wk|Wv, contiguous bf16 destination.
// ---------------------------------------------------------------------------
__global__ __launch_bounds__(256) void cvt_all_k(const float* __restrict__ h,
                                                 const float* __restrict__ wq,
                                                 const float* __restrict__ wk,
                                                 const float* __restrict__ wv,
                                                 us* __restrict__ dst) {
  long blk = blockIdx.x;
  const float* src;
  long off;
  if (blk < 4096)        { src = h;  off = 0; }
  else if (blk < 12288)  { src = wq; off = 4096; }
  else if (blk < 14336)  { src = wk; off = 12288; }
  else                   { src = wv; off = 14336; }
  long i = (blk - off) * 2048 + (long)threadIdx.x * 8;
  long o = blk * 2048 + (long)threadIdx.x * 8;
  float4v a = *(const float4v*)(src + i);
  float4v b = *(const float4v*)(src + i + 4);
  u8v v;
  v[0] = f2b(a[0]); v[1] = f2b(a[1]); v[2] = f2b(a[2]); v[3] = f2b(a[3]);
  v[4] = f2b(b[0]); v[5] = f2b(b[1]); v[6] = f2b(b[2]); v[7] = f2b(b[3]);
  *(u8v*)(dst + o) = v;
}

// ---------------------------------------------------------------------------
// m201-style 8-phase bf16 GEMM: C[M,N] = A[M,K] * W[N,K]^T   (round-5 core)
// Tile = (2*AH) x 256, BK=64, 512 threads (8 waves, 2M x 4N).
// LDS: A[2][2][AH*64] + B[2][2][128*64]; AH=128 -> 128 KiB, AH=64 -> 96 KiB.
// Phases/K-tile: q(0,0) q(0,1) q(1,1) q(1,0); b0 frags resident (phase 4 has
// no ds_reads); one half-tile staged per phase into the just-freed slot;
// counted vmcnt(2*LA+2) once per K-tile (3 half-tiles in flight).
// ---------------------------------------------------------------------------
template <int AH, bool F32OUT, bool CVTTAIL>
__global__ __launch_bounds__(512, 2) void gemm8p(const us* __restrict__ A,
                                                 const us* __restrict__ W,
                                                 void* __restrict__ Cv,
                                                 int K, int nkt, int ldc,
                                                 int cm, int cn, int ncn,
                                                 int nGemm,
                                                 const float* __restrict__ csrc,
                                                 us* __restrict__ cdst) {
  if constexpr (CVTTAIL) {
    if ((int)blockIdx.x >= nGemm) {
      long c = (long)((int)blockIdx.x - nGemm) * 512 + threadIdx.x;
      for (; c < 2097152; c += 64 * 512) {      // 16,777,216 elems / 8
        long i = c * 8;
        float4v x = *(const float4v*)(csrc + i);
        float4v y = *(const float4v*)(csrc + i + 4);
        u8v v;
        v[0] = f2b(x[0]); v[1] = f2b(x[1]); v[2] = f2b(x[2]); v[3] = f2b(x[3]);
        v[4] = f2b(y[0]); v[5] = f2b(y[1]); v[6] = f2b(y[2]); v[7] = f2b(y[3]);
        *(u8v*)(cdst + i) = v;
      }
      return;
    }
  }

  constexpr int FR = AH / 32;          // A row-frags per wave per half
  constexpr int LA = AH / 64;          // gload_lds per thread per A-half
  constexpr int VM = 2 * LA + 2;       // counted vmcnt (keep kt+2's loads)

  __shared__ __align__(16) us Ah[2][2][AH * 64];
  __shared__ __align__(16) us Bh[2][2][128 * 64];
  const int tid = threadIdx.x, lane = tid & 63, w = tid >> 6;
  const int wr = w >> 2, wc = w & 3;
  const int lr = lane & 15, lg = lane >> 4;

  // 2D XCD chunking: xcd = bid&7 owns a cm x cn tile chunk, M-fastest inside.
  const int xcd = (int)blockIdx.x & 7;
  const int i2 = (int)blockIdx.x >> 3;
  const int im = i2 % cm, itn = i2 / cm;
  const long m0 = (long)((xcd / ncn) * cm + im) * (2 * AH);
  const long n0 = (long)((xcd % ncn) * cn + itn) * 256;

  // staging geometry: thread covers 16B chunk(s) l*512+tid of a half-tile
  const int rA0 = tid >> 3;                        // row for chunk l=0
  const int sc0 = ((tid & 7) ^ (rA0 & 7)) << 3;    // inverse-swizzled src col

#define STGH(dst, src, LOADS)                                           \
  do {                                                                  \
    const us* _s = (src);                                               \
    us* _d = (dst);                                                     \
    _Pragma("unroll") for (int l = 0; l < (LOADS); ++l)                 \
      gload16(_s + (long)(rA0 + l * 64) * K + sc0, _d + (l * 512 + tid) * 8); \
  } while (0)

  const us* Asrc = A + m0 * K;     // half h at + h*AH*K, K-tile kt at + kt*64
  const us* Bsrc = W + n0 * K;
  const long hKA = (long)AH * K;
  const long hKB = (long)128 * K;

  // fragment read offsets (elements; row*64 + swizzled-chunk*8)
  const int ra = wr * (AH / 2) + lr, rb = wc * 32 + lr;
  const int offA0 = ra * 64 + ((lg ^ (ra & 7)) << 3);
  const int offA1 = ra * 64 + (((4 + lg) ^ (ra & 7)) << 3);
  const int offB0 = rb * 64 + ((lg ^ (rb & 7)) << 3);
  const int offB1 = rb * 64 + (((4 + lg) ^ (rb & 7)) << 3);

  f4v acc[2 * FR][4];
#pragma unroll
  for (int i = 0; i < 2 * FR; ++i)
#pragma unroll
    for (int j = 0; j < 4; ++j) acc[i][j] = (f4v){0.f, 0.f, 0.f, 0.f};

  const int nk = nkt;

  // prologue: tile0 {A0,B0,B1,A1} (8 loads) then tile1 {A0,B1,A1} (6 loads)
  STGH(Ah[0][0], Asrc, LA);
  STGH(Bh[0][0], Bsrc, 2);
  STGH(Bh[0][1], Bsrc + hKB, 2);
  STGH(Ah[0][1], Asrc + hKA, LA);
  STGH(Ah[1][0], Asrc + 64, LA);
  STGH(Bh[1][1], Bsrc + hKB + 64, 2);
  STGH(Ah[1][1], Asrc + hKA + 64, LA);
  asm volatile("s_waitcnt vmcnt(%0)" :: "i"(VM) : "memory");   // tile 0 landed
  BARRIER();

  s8v a[FR][2], b0[2][2], b1[2][2];

#define RD_A(H)                                                         \
  _Pragma("unroll") for (int f = 0; f < FR; ++f) {                      \
    a[f][0] = *(const s8v*)(&Ah[d][H][offA0 + f * 1024]);               \
    a[f][1] = *(const s8v*)(&Ah[d][H][offA1 + f * 1024]);               \
  }
#define RD_B(BB, H)                                                     \
  _Pragma("unroll") for (int g = 0; g < 2; ++g) {                       \
    BB[g][0] = *(const s8v*)(&Bh[d][H][offB0 + g * 1024]);              \
    BB[g][1] = *(const s8v*)(&Bh[d][H][offB1 + g * 1024]);              \
  }
#define QUAD(QM, QN, BB)                                                \
  __builtin_amdgcn_s_setprio(1);                                        \
  _Pragma("unroll") for (int f = 0; f < FR; ++f)                        \
  _Pragma("unroll") for (int g = 0; g < 2; ++g) {                       \
    f4v t = acc[QM * FR + f][QN * 2 + g];                               \
    t = __builtin_amdgcn_mfma_f32_16x16x32_bf16(a[f][0], BB[g][0], t, 0, 0, 0); \
    t = __builtin_amdgcn_mfma_f32_16x16x32_bf16(a[f][1], BB[g][1], t, 0, 0, 0); \
    acc[QM * FR + f][QN * 2 + g] = t;                                   \
  }                                                                     \
  __builtin_amdgcn_s_setprio(0);
#define PREMFMA()                                                       \
  BARRIER();                                                            \
  asm volatile("s_waitcnt lgkmcnt(0)" ::: "memory");                    \
  SB();

  for (int kt = 0; kt < nk; ++kt) {
    const int d = kt & 1;
    const long kb2 = (long)(kt + 2) * 64;
    const bool p1 = (kt + 1 < nk), p2 = (kt + 2 < nk);

    // ---- phase 1: q(0,0); stage B0(kt+1) -> other dbuf ----
    RD_A(0)
    RD_B(b0, 0)
    if (p1) STGH(Bh[d ^ 1][0], Bsrc + (long)(kt + 1) * 64, 2);
    PREMFMA()
    QUAD(0, 0, b0)
    BARRIER();

    // ---- phase 2: q(0,1); stage A0(kt+2) into freed A0 slot ----
    RD_B(b1, 1)
    if (p2) STGH(Ah[d][0], Asrc + kb2, LA);
    PREMFMA()
    QUAD(0, 1, b1)
    BARRIER();

    // ---- phase 3: q(1,1); stage B1(kt+2) into freed B1 slot ----
    RD_A(1)
    if (p2) STGH(Bh[d][1], Bsrc + hKB + kb2, 2);
    PREMFMA()
    QUAD(1, 1, b1)
    BARRIER();

    // ---- phase 4: q(1,0); no ds_reads; stage A1(kt+2); counted vmcnt ----
    if (p2) STGH(Ah[d][1], Asrc + hKA + kb2, LA);
    PREMFMA()
    QUAD(1, 0, b0)
    if (p2) asm volatile("s_waitcnt vmcnt(%0)" :: "i"(VM) : "memory");
    else    asm volatile("s_waitcnt vmcnt(0)" ::: "memory");
    BARRIER();
  }

  // ---- epilogue ----
#pragma unroll
  for (int qm = 0; qm < 2; ++qm)
#pragma unroll
    for (int f = 0; f < FR; ++f) {
      long row = m0 + qm * AH + wr * (AH / 2) + f * 16 + lg * 4;
#pragma unroll
      for (int qn = 0; qn < 2; ++qn)
#pragma unroll
        for (int g = 0; g < 2; ++g) {
          long col = n0 + qn * 128 + wc * 32 + g * 16 + lr;
          f4v v = acc[qm * FR + f][qn * 2 + g];
          if constexpr (F32OUT) {
            float* C = (float*)Cv;
#pragma unroll
            for (int r = 0; r < 4; ++r) C[(row + r) * ldc + col] = v[r];
          } else {
            us* C = (us*)Cv;
#pragma unroll
            for (int r = 0; r < 4; ++r) C[(row + r) * ldc + col] = f2b(v[r]);
          }
        }
    }
#undef STGH
#undef RD_A
#undef RD_B
#undef QUAD
#undef PREMFMA
}

// ---------------------------------------------------------------------------
// Per-head RMSNorm (D=128) + RoPE for K HEADS ONLY, in-place, vectorized.
// (Q heads are normalized+roped inside the attention prologue.)
// One wave per (row, khead); 16384 waves -> grid 4096.
// ---------------------------------------------------------------------------
__global__ __launch_bounds__(256) void rms_rope_k(us* __restrict__ qkv,
                                                  const float* __restrict__ fc,
                                                  const float* __restrict__ kw) {
  int idx = blockIdx.x * 4 + (threadIdx.x >> 6);
  int lane = threadIdx.x & 63;
  int head = idx & 7;                  // 8 K heads
  int row = idx >> 3;                  // b*1024 + s
  int s = row & 1023;
  us* p = qkv + (long)row * 6144 + 4096 + head * 128;
  const float* w = kw;

  unsigned v = ((const unsigned*)p)[lane];
  float x0 = b2f((us)(v & 0xffff)), x1 = b2f((us)(v >> 16));
  float ss = x0 * x0 + x1 * x1;
#pragma unroll
  for (int off = 32; off; off >>= 1) ss += __shfl_xor(ss, off);
  float r = rsqrtf(ss * (1.0f / 128.0f) + 1e-6f);
  float2v wv = ((const float2v*)w)[lane];
  float y0 = x0 * r * wv[0], y1 = x1 * r * wv[1];
  float py0 = __shfl(y0, lane ^ 32);
  float py1 = __shfl(y1, lane ^ 32);
  float2v cv = ((const float2v*)(fc + (long)s * 128))[lane];
  const float* sbase = (lane < 32) ? (fc + 2 * 1024 * 128) : (fc + 1024 * 128);
  float2v sv = ((const float2v*)(sbase + (long)s * 128))[lane];
  float e0 = y0 * cv[0] + py0 * sv[0];
  float e1 = y1 * cv[1] + py1 * sv[1];
  ((unsigned*)p)[lane] = (unsigned)f2b(e0) | ((unsigned)f2b(e1) << 16);
}

// ---------------------------------------------------------------------------
// Flash attention (no mask), GQA 4:1. Block = 4 waves = 64 q-rows; 64-key
// tiles. Q RMSNorm+RoPE fused in the prologue (lane-local: partner d^64 is
// qf[ks^2], same lane; row-sumsq reduces over lg via 2 shuffles).
// ---------------------------------------------------------------------------
__global__ __launch_bounds__(256) void attn_k(const us* __restrict__ qkv,
                                              us* __restrict__ ao,
                                              const float* __restrict__ fc,
                                              const float* __restrict__ qw) {
  __shared__ us Kt[64 * 128];   // [key][d], rows 256B, XOR-swizzled
  __shared__ us Vt[128 * 72];   // [d][key], padded rows (144B)
  __shared__ us Pl[4 * 1024];   // per-wave 16x64 P, XOR-swizzled

  const int bid = blockIdx.x;
  const int qt = bid & 15;
  const int h = (bid >> 4) & 31;
  const int b = bid >> 9;
  const int kvh = h >> 2;
  const int tid = threadIdx.x, lane = tid & 63, w = tid >> 6;
  const int lr = lane & 15, lg = lane >> 4;

  // ---- Q prologue: load raw Q frags, apply RMSNorm + RoPE in-register ----
  const int srow = qt * 64 + w * 16 + lr;        // sequence position
  const us* Qb = qkv + (long)(b * 1024 + srow) * 6144 + h * 128;
  s8v qr[4];
#pragma unroll
  for (int ks = 0; ks < 4; ++ks) qr[ks] = *(const s8v*)(Qb + ks * 32 + lg * 8);

  float ssq = 0.f;
#pragma unroll
  for (int ks = 0; ks < 4; ++ks)
#pragma unroll
    for (int j = 0; j < 8; ++j) {
      float x = b2f((us)qr[ks][j]);
      ssq += x * x;
    }
  ssq += __shfl_xor(ssq, 16);
  ssq += __shfl_xor(ssq, 32);
  const float rr = rsqrtf(ssq * (1.0f / 128.0f) + 1e-6f);

  const float* cosp = fc + (long)srow * 128;
  const float* sinp = fc + 1024 * 128 + (long)srow * 128;
  s8v qf[4];
#pragma unroll
  for (int ks = 0; ks < 4; ++ks) {
    const int d0 = ks * 32 + lg * 8;
    const int dp = d0 ^ 64;                       // partner block
    const float sgn = (ks < 2) ? -1.f : 1.f;      // e[:64]+=x[64:]*nsin; e[64:]+=x[:64]*sin
#pragma unroll
    for (int j = 0; j < 8; ++j) {
      float y  = b2f((us)qr[ks][j])     * rr * qw[d0 + j];
      float yp = b2f((us)qr[ks ^ 2][j]) * rr * qw[dp + j];
      float e = y * cosp[d0 + j] + yp * sgn * sinp[d0 + j];
      qf[ks][j] = (short)f2b(e);
    }
  }

  f4v o[8];
#pragma unroll
  for (int n = 0; n < 8; ++n) o[n] = (f4v){0.f, 0.f, 0.f, 0.f};
  float m[4], l[4];
#pragma unroll
  for (int r = 0; r < 4; ++r) { m[r] = -1e30f; l[r] = 0.f; }

  const float SL = 0.08838834764831845f * 1.4426950408889634f;  // D^-1/2 * log2e
  const long krow = (long)b * 1024 * 6144 + 4096 + kvh * 128;
  const long vrow = (long)b * 1024 * 6144 + 5120 + kvh * 128;

  for (int kt = 0; kt < 16; ++kt) {
    __syncthreads();
    // ---- stage K tile (swizzled source -> linear LDS) ----
#pragma unroll
    for (int t = 0; t < 4; ++t) {
      int c = t * 256 + tid;
      int row = c >> 4;
      int sc = (c & 15) ^ (row & 7);
      gload16(qkv + krow + (long)(kt * 64 + row) * 6144 + sc * 8, &Kt[c * 8]);
    }
    // ---- stage V transposed (key-pair packed b32 writes) ----
#pragma unroll
    for (int t = 0; t < 2; ++t) {
      int c = t * 256 + tid;                     // 0..511 pair-chunks
      int kp = c & 31;                           // keys 2kp, 2kp+1
      int d0 = (c >> 5) * 8;                     // 0..120
      const us* vsrc = qkv + vrow + (long)(kt * 64) * 6144 + d0;
      s8v va = *(const s8v*)(vsrc + (long)(2 * kp) * 6144);
      s8v vb = *(const s8v*)(vsrc + (long)(2 * kp + 1) * 6144);
#pragma unroll
      for (int i = 0; i < 8; ++i) {
        unsigned pk = (unsigned)(us)va[i] | ((unsigned)(us)vb[i] << 16);
        *(unsigned*)&Vt[(d0 + i) * 72 + 2 * kp] = pk;
      }
    }
    __syncthreads();

    // ---- S = Q K^T ----
    f4v sacc[4];
#pragma unroll
    for (int j = 0; j < 4; ++j) sacc[j] = (f4v){0.f, 0.f, 0.f, 0.f};
    __builtin_amdgcn_s_setprio(1);
#pragma unroll
    for (int ks = 0; ks < 4; ++ks) {
#pragma unroll
      for (int j = 0; j < 4; ++j) {
        int key = j * 16 + lr;
        s8v kf = *(const s8v*)&Kt[key * 128 + (((ks * 64 + lg * 16) ^ ((key & 7) << 4)) >> 1)];
        sacc[j] = __builtin_amdgcn_mfma_f32_16x16x32_bf16(qf[ks], kf, sacc[j], 0, 0, 0);
      }
    }
    __builtin_amdgcn_s_setprio(0);

    // ---- online softmax (exp2 domain) ----
    float sm[4];
#pragma unroll
    for (int r = 0; r < 4; ++r)
      sm[r] = fmaxf(fmaxf(sacc[0][r], sacc[1][r]), fmaxf(sacc[2][r], sacc[3][r]));
#pragma unroll
    for (int off = 1; off < 16; off <<= 1)
#pragma unroll
      for (int r = 0; r < 4; ++r) sm[r] = fmaxf(sm[r], __shfl_xor(sm[r], off));
    float alpha[4];
#pragma unroll
    for (int r = 0; r < 4; ++r) {
      float nm = fmaxf(m[r], sm[r] * SL);
      alpha[r] = exp2f(m[r] - nm);
      m[r] = nm;
      l[r] *= alpha[r];
    }
#pragma unroll
    for (int n = 0; n < 8; ++n)
#pragma unroll
      for (int r = 0; r < 4; ++r) o[n][r] *= alpha[r];

    us* pw = Pl + w * 1024;
#pragma unroll
    for (int j = 0; j < 4; ++j)
#pragma unroll
      for (int r = 0; r < 4; ++r) {
        float p = exp2f(sacc[j][r] * SL - m[r]);
        l[r] += p;
        int prow = lg * 4 + r, pcol = j * 16 + lr;
        pw[(prow * 128 + ((pcol * 2) ^ ((prow & 7) << 4))) >> 1] = f2b(p);
      }

    // ---- O += P V ----
    __builtin_amdgcn_s_setprio(1);
#pragma unroll
    for (int ks = 0; ks < 2; ++ks) {
      int bo = ks * 64 + lg * 16;
      s8v pf = *(const s8v*)&Pl[w * 1024 + ((lr * 128 + (bo ^ ((lr & 7) << 4))) >> 1)];
#pragma unroll
      for (int n = 0; n < 8; ++n) {
        s8v vf = *(const s8v*)&Vt[(n * 16 + lr) * 72 + ks * 32 + lg * 8];
        o[n] = __builtin_amdgcn_mfma_f32_16x16x32_bf16(pf, vf, o[n], 0, 0, 0);
      }
    }
    __builtin_amdgcn_s_setprio(0);
  }

#pragma unroll
  for (int off = 1; off < 16; off <<= 1)
#pragma unroll
    for (int r = 0; r < 4; ++r) l[r] += __shfl_xor(l[r], off);
  float inv[4];
#pragma unroll
  for (int r = 0; r < 4; ++r) inv[r] = 1.f / l[r];
  const long ob = (long)(b * 1024 + qt * 64 + w * 16) * 4096 + h * 128;
#pragma unroll
  for (int n = 0; n < 8; ++n)
#pragma unroll
    for (int r = 0; r < 4; ++r)
      ao[ob + (long)(lg * 4 + r) * 4096 + n * 16 + lr] = f2b(o[n][r] * inv[r]);
}

// ---------------------------------------------------------------------------
// Launch
// ---------------------------------------------------------------------------
extern "C" void kernel_launch(void* const* d_in, const int* in_sizes, int n_in,
                              void* d_out, int out_size, void* d_ws, size_t ws_size,
                              hipStream_t stream) {
  const float* hidden = (const float*)d_in[0];
  const float* fc     = (const float*)d_in[1];
  const float* Wq     = (const float*)d_in[2];
  const float* Wk     = (const float*)d_in[3];
  const float* Wv     = (const float*)d_in[4];
  const float* Wo     = (const float*)d_in[5];
  const float* qw     = (const float*)d_in[6];
  const float* kw     = (const float*)d_in[7];

  us* hb  = (us*)d_ws;                          // [2048][4096] bf16
  us* wb  = hb + (long)2048 * 4096;             // [10240][4096] bf16 (Wq|Wk|Wv|Wo)
  us* wbo = wb + (long)6144 * 4096;             // Wo bf16 [4096][4096]
  us* qkv = wbo + (long)4096 * 4096;            // [2048][6144] bf16
  us* ao  = qkv + (long)2048 * 6144;            // [2048][4096] bf16

  // convert hidden|Wq|Wk|Wv -> contiguous bf16 at hb (Wo converted in-gemm)
  cvt_all_k<<<16384, 256, 0, stream>>>(hidden, Wq, Wk, Wv, hb);

  // fused QKV projection (192 gemm blocks: 8M x 24N, XCD chunks 4Mx6N)
  // + Wo convert (64 tail blocks)
  gemm8p<128, false, true><<<256, 512, 0, stream>>>(
      hb, wb, qkv, 4096, 64, 6144, 4, 6, 4, 192, Wo, wbo);

  // K-head RMSNorm + RoPE in place (Q handled inside attn)
  rms_rope_k<<<4096, 256, 0, stream>>>(qkv, fc, kw);

  // flash attention (Q rms+rope fused) -> bf16 [2048][4096]
  attn_k<<<1024, 256, 0, stream>>>(qkv, ao, fc, qw);

  // output projection: BM=128, grid 256 (16M x 16N, XCD chunks 8Mx4N),
  // full-K, f32 -> d_out
  gemm8p<64, true, false><<<256, 512, 0, stream>>>(
      ao, wbo, d_out, 4096, 64, 4096, 8, 4, 4, 256, nullptr, nullptr);
}

// Round 9
// 322.940 us; speedup vs baseline: 1.8015x; 1.0451x over previous
//
#include <hip/hip_runtime.h>

// ---------------------------------------------------------------------------
// Qwen3-style attention block on MI355X (gfx950), bf16 MFMA pipeline.
// B=2, S=1024, HID=4096, H=32, KV=8, D=128.
// Stages: cvt(h,Wq,Wk,Wv) -> QKV GEMM (+Wo-cvt tail) -> K-RMSNorm+RoPE
//         -> flash attn (Q-RMSNorm+RoPE fused) -> out GEMM (gemm2p).
// gemm2p (new): 1 barrier-pair per K-tile, tile 256x128, wave=64x64,
// reads retire pre-barrier (cross-wave WAR-safe A-stage post-barrier),
// counted vmcnt(4) keeps next-next A in flight. Grid 256 = full chip.
// ---------------------------------------------------------------------------

typedef __attribute__((ext_vector_type(8))) short s8v;            // 8 bf16 (4 VGPR)
typedef __attribute__((ext_vector_type(4))) float f4v;
typedef __attribute__((ext_vector_type(8))) unsigned short u8v;
typedef __attribute__((ext_vector_type(4))) float float4v;
typedef __attribute__((ext_vector_type(2))) float float2v;
typedef unsigned short us;

#define SB() __builtin_amdgcn_sched_barrier(0)

__device__ __forceinline__ void BARRIER() {
  asm volatile("" ::: "memory");
  __builtin_amdgcn_s_barrier();
  asm volatile("" ::: "memory");
}

__device__ __forceinline__ us f2b(float f) {
  unsigned u = __builtin_bit_cast(unsigned, f);
  u += 0x7fffu + ((u >> 16) & 1u);            // round-to-nearest-even
  return (us)(u >> 16);
}
__device__ __forceinline__ float b2f(us h) {
  return __builtin_bit_cast(float, (unsigned)h << 16);
}

__device__ __forceinline__ void gload16(const void* g, void* l) {
  __builtin_amdgcn_global_load_lds(
      (const __attribute__((address_space(1))) unsigned int*)g,
      (__attribute__((address_space(3))) unsigned int*)l, 16, 0, 0);
}

// ---------------------------------------------------------------------------
// Fused f32 -> bf16 convert: hidden|Wq|Wk|Wv, contiguous bf16 destination.
// ---------------------------------------------------------------------------
__global__ __launch_bounds__(256) void cvt_all_k(const float* __restrict__ h,
                                                 const float* __restrict__ wq,
                                                 const float* __restrict__ wk,
                                                 const float* __restrict__ wv,
                                                 us* __restrict__ dst) {
  long blk = blockIdx.x;
  const float* src;
  long off;
  if (blk < 4096)        { src = h;  off = 0; }
  else if (blk < 12288)  { src = wq; off = 4096; }
  else if (blk < 14336)  { src = wk; off = 12288; }
  else                   { src = wv; off = 14336; }
  long i = (blk - off) * 2048 + (long)threadIdx.x * 8;
  long o = blk * 2048 + (long)threadIdx.x * 8;
  float4v a = *(const float4v*)(src + i);
  float4v b = *(const float4v*)(src + i + 4);
  u8v v;
  v[0] = f2b(a[0]); v[1] = f2b(a[1]); v[2] = f2b(a[2]); v[3] = f2b(a[3]);
  v[4] = f2b(b[0]); v[5] = f2b(b[1]); v[6] = f2b(b[2]); v[7] = f2b(b[3]);
  *(u8v*)(dst + o) = v;
}

// ---------------------------------------------------------------------------
// m201-style 8-phase bf16 GEMM (QKV): C[M,N] = A[M,K] * W[N,K]^T
// (unchanged round-8 core: 256x256 tile, counted vmcnt(6), chunk-XOR swizzle)
// ---------------------------------------------------------------------------
template <int AH, bool F32OUT, bool CVTTAIL>
__global__ __launch_bounds__(512, 2) void gemm8p(const us* __restrict__ A,
                                                 const us* __restrict__ W,
                                                 void* __restrict__ Cv,
                                                 int K, int nkt, int ldc,
                                                 int cm, int cn, int ncn,
                                                 int nGemm,
                                                 const float* __restrict__ csrc,
                                                 us* __restrict__ cdst) {
  if constexpr (CVTTAIL) {
    if ((int)blockIdx.x >= nGemm) {
      long c = (long)((int)blockIdx.x - nGemm) * 512 + threadIdx.x;
      for (; c < 2097152; c += 64 * 512) {      // 16,777,216 elems / 8
        long i = c * 8;
        float4v x = *(const float4v*)(csrc + i);
        float4v y = *(const float4v*)(csrc + i + 4);
        u8v v;
        v[0] = f2b(x[0]); v[1] = f2b(x[1]); v[2] = f2b(x[2]); v[3] = f2b(x[3]);
        v[4] = f2b(y[0]); v[5] = f2b(y[1]); v[6] = f2b(y[2]); v[7] = f2b(y[3]);
        *(u8v*)(cdst + i) = v;
      }
      return;
    }
  }

  constexpr int FR = AH / 32;          // A row-frags per wave per half
  constexpr int LA = AH / 64;          // gload_lds per thread per A-half
  constexpr int VM = 2 * LA + 2;       // counted vmcnt (keep kt+2's loads)

  __shared__ __align__(16) us Ah[2][2][AH * 64];
  __shared__ __align__(16) us Bh[2][2][128 * 64];
  const int tid = threadIdx.x, lane = tid & 63, w = tid >> 6;
  const int wr = w >> 2, wc = w & 3;
  const int lr = lane & 15, lg = lane >> 4;

  const int xcd = (int)blockIdx.x & 7;
  const int i2 = (int)blockIdx.x >> 3;
  const int im = i2 % cm, itn = i2 / cm;
  const long m0 = (long)((xcd / ncn) * cm + im) * (2 * AH);
  const long n0 = (long)((xcd % ncn) * cn + itn) * 256;

  const int rA0 = tid >> 3;
  const int sc0 = ((tid & 7) ^ (rA0 & 7)) << 3;

#define STGH(dst, src, LOADS)                                           \
  do {                                                                  \
    const us* _s = (src);                                               \
    us* _d = (dst);                                                     \
    _Pragma("unroll") for (int l = 0; l < (LOADS); ++l)                 \
      gload16(_s + (long)(rA0 + l * 64) * K + sc0, _d + (l * 512 + tid) * 8); \
  } while (0)

  const us* Asrc = A + m0 * K;
  const us* Bsrc = W + n0 * K;
  const long hKA = (long)AH * K;
  const long hKB = (long)128 * K;

  const int ra = wr * (AH / 2) + lr, rb = wc * 32 + lr;
  const int offA0 = ra * 64 + ((lg ^ (ra & 7)) << 3);
  const int offA1 = ra * 64 + (((4 + lg) ^ (ra & 7)) << 3);
  const int offB0 = rb * 64 + ((lg ^ (rb & 7)) << 3);
  const int offB1 = rb * 64 + (((4 + lg) ^ (rb & 7)) << 3);

  f4v acc[2 * FR][4];
#pragma unroll
  for (int i = 0; i < 2 * FR; ++i)
#pragma unroll
    for (int j = 0; j < 4; ++j) acc[i][j] = (f4v){0.f, 0.f, 0.f, 0.f};

  const int nk = nkt;

  STGH(Ah[0][0], Asrc, LA);
  STGH(Bh[0][0], Bsrc, 2);
  STGH(Bh[0][1], Bsrc + hKB, 2);
  STGH(Ah[0][1], Asrc + hKA, LA);
  STGH(Ah[1][0], Asrc + 64, LA);
  STGH(Bh[1][1], Bsrc + hKB + 64, 2);
  STGH(Ah[1][1], Asrc + hKA + 64, LA);
  asm volatile("s_waitcnt vmcnt(%0)" :: "i"(VM) : "memory");
  BARRIER();

  s8v a[FR][2], b0[2][2], b1[2][2];

#define RD_A(H)                                                         \
  _Pragma("unroll") for (int f = 0; f < FR; ++f) {                      \
    a[f][0] = *(const s8v*)(&Ah[d][H][offA0 + f * 1024]);               \
    a[f][1] = *(const s8v*)(&Ah[d][H][offA1 + f * 1024]);               \
  }
#define RD_B(BB, H)                                                     \
  _Pragma("unroll") for (int g = 0; g < 2; ++g) {                       \
    BB[g][0] = *(const s8v*)(&Bh[d][H][offB0 + g * 1024]);              \
    BB[g][1] = *(const s8v*)(&Bh[d][H][offB1 + g * 1024]);              \
  }
#define QUAD(QM, QN, BB)                                                \
  __builtin_amdgcn_s_setprio(1);                                        \
  _Pragma("unroll") for (int f = 0; f < FR; ++f)                        \
  _Pragma("unroll") for (int g = 0; g < 2; ++g) {                       \
    f4v t = acc[QM * FR + f][QN * 2 + g];                               \
    t = __builtin_amdgcn_mfma_f32_16x16x32_bf16(a[f][0], BB[g][0], t, 0, 0, 0); \
    t = __builtin_amdgcn_mfma_f32_16x16x32_bf16(a[f][1], BB[g][1], t, 0, 0, 0); \
    acc[QM * FR + f][QN * 2 + g] = t;                                   \
  }                                                                     \
  __builtin_amdgcn_s_setprio(0);
#define PREMFMA()                                                       \
  BARRIER();                                                            \
  asm volatile("s_waitcnt lgkmcnt(0)" ::: "memory");                    \
  SB();

  for (int kt = 0; kt < nk; ++kt) {
    const int d = kt & 1;
    const long kb2 = (long)(kt + 2) * 64;
    const bool p1 = (kt + 1 < nk), p2 = (kt + 2 < nk);

    RD_A(0)
    RD_B(b0, 0)
    if (p1) STGH(Bh[d ^ 1][0], Bsrc + (long)(kt + 1) * 64, 2);
    PREMFMA()
    QUAD(0, 0, b0)
    BARRIER();

    RD_B(b1, 1)
    if (p2) STGH(Ah[d][0], Asrc + kb2, LA);
    PREMFMA()
    QUAD(0, 1, b1)
    BARRIER();

    RD_A(1)
    if (p2) STGH(Bh[d][1], Bsrc + hKB + kb2, 2);
    PREMFMA()
    QUAD(1, 1, b1)
    BARRIER();

    if (p2) STGH(Ah[d][1], Asrc + hKA + kb2, LA);
    PREMFMA()
    QUAD(1, 0, b0)
    if (p2) asm volatile("s_waitcnt vmcnt(%0)" :: "i"(VM) : "memory");
    else    asm volatile("s_waitcnt vmcnt(0)" ::: "memory");
    BARRIER();
  }

#pragma unroll
  for (int qm = 0; qm < 2; ++qm)
#pragma unroll
    for (int f = 0; f < FR; ++f) {
      long row = m0 + qm * AH + wr * (AH / 2) + f * 16 + lg * 4;
#pragma unroll
      for (int qn = 0; qn < 2; ++qn)
#pragma unroll
        for (int g = 0; g < 2; ++g) {
          long col = n0 + qn * 128 + wc * 32 + g * 16 + lr;
          f4v v = acc[qm * FR + f][qn * 2 + g];
          if constexpr (F32OUT) {
            float* C = (float*)Cv;
#pragma unroll
            for (int r = 0; r < 4; ++r) C[(row + r) * ldc + col] = v[r];
          } else {
            us* C = (us*)Cv;
#pragma unroll
            for (int r = 0; r < 4; ++r) C[(row + r) * ldc + col] = f2b(v[r]);
          }
        }
    }
#undef STGH
#undef RD_A
#undef RD_B
#undef QUAD
#undef PREMFMA
}

// ---------------------------------------------------------------------------
// gemm2p (out-proj): C[2048,4096] f32 = A[2048,K]bf16 * W[4096,K]^T bf16
// Tile 256(M,A) x 128(N,W), BK=64. 8 waves = 4M x 2N, wave = 64x64.
// LDS: Ab[2][256*64] + Bb[2][128*64] = 96 KiB (double-buffered wholes).
// Per K-tile (ONE barrier pair):
//   {16 ds_read (all frags); stage B(kt+1)->B[d^1]; lgkm(0); BARRIER;
//    stage A(kt+2)->A[d]; 32 MFMA (setprio); vmcnt(4); BARRIER}
// Safety: per-wave lgkm(0) BEFORE the barrier retires all A[d]/B[d] reads,
// so the post-barrier A-stage cannot overwrite unread data (cross-wave WAR).
// vmcnt(4): in-flight = A(kt+1)4 + B(kt+1)2 + A(kt+2)4 = 10 -> drain 6
// oldest (A/B for kt+1 landed), keep A(kt+2) flying. Grid 256: 8M x 32N,
// XCD owns 8M x 4N (M-fastest).
// ---------------------------------------------------------------------------
__global__ __launch_bounds__(512) void gemm2p(const us* __restrict__ A,
                                              const us* __restrict__ W,
                                              float* __restrict__ C) {
  constexpr int K = 4096, nk = 64, ldc = 4096;
  __shared__ __align__(16) us Ab[2][256 * 64];
  __shared__ __align__(16) us Bb[2][128 * 64];
  const int tid = threadIdx.x, lane = tid & 63, w = tid >> 6;
  const int wm = w & 3, wn = w >> 2;
  const int lr = lane & 15, lg = lane >> 4;

  // XCD 2D chunk: xcd owns all 8 M-tiles x 4 N-tiles, M-fastest.
  const int xcd = (int)blockIdx.x & 7;
  const int i2 = (int)blockIdx.x >> 3;
  const long m0 = (long)(i2 & 7) * 256;
  const long n0 = (long)(xcd * 4 + (i2 >> 3)) * 128;

  const int rA0 = tid >> 3;
  const int sc0 = ((tid & 7) ^ (rA0 & 7)) << 3;
  const us* Asrc = A + m0 * K;
  const us* Bsrc = W + n0 * K;

#define STGA2(buf, src)                                                  \
  do {                                                                   \
    const us* _s = (src);                                                \
    _Pragma("unroll") for (int l = 0; l < 4; ++l)                        \
      gload16(_s + (long)(rA0 + l * 64) * K + sc0, &Ab[buf][(l * 512 + tid) * 8]); \
  } while (0)
#define STGB2(buf, src)                                                  \
  do {                                                                   \
    const us* _s = (src);                                                \
    _Pragma("unroll") for (int l = 0; l < 2; ++l)                        \
      gload16(_s + (long)(rA0 + l * 64) * K + sc0, &Bb[buf][(l * 512 + tid) * 8]); \
  } while (0)

  const int ra = wm * 64 + lr;
  const int rb = wn * 64 + lr;
  const int offA0 = ra * 64 + ((lg ^ (ra & 7)) << 3);
  const int offA1 = ra * 64 + (((4 + lg) ^ (ra & 7)) << 3);
  const int offB0 = rb * 64 + ((lg ^ (rb & 7)) << 3);
  const int offB1 = rb * 64 + (((4 + lg) ^ (rb & 7)) << 3);

  f4v acc[4][4];
#pragma unroll
  for (int f = 0; f < 4; ++f)
#pragma unroll
    for (int g = 0; g < 4; ++g) acc[f][g] = (f4v){0.f, 0.f, 0.f, 0.f};

  // prologue: A(0), B(0), A(1); keep A(1) in flight
  STGA2(0, Asrc);
  STGB2(0, Bsrc);
  STGA2(1, Asrc + 64);
  asm volatile("s_waitcnt vmcnt(4)" ::: "memory");
  BARRIER();

  for (int kt = 0; kt < nk; ++kt) {
    const int d = kt & 1;
    const bool p1 = (kt + 1 < nk), p2 = (kt + 2 < nk);

    // all 16 fragment reads for this tile
    s8v a[4][2], b[4][2];
#pragma unroll
    for (int f = 0; f < 4; ++f) {
      a[f][0] = *(const s8v*)(&Ab[d][offA0 + f * 1024]);
      a[f][1] = *(const s8v*)(&Ab[d][offA1 + f * 1024]);
    }
#pragma unroll
    for (int g = 0; g < 4; ++g) {
      b[g][0] = *(const s8v*)(&Bb[d][offB0 + g * 1024]);
      b[g][1] = *(const s8v*)(&Bb[d][offB1 + g * 1024]);
    }
    if (p1) STGB2(d ^ 1, Bsrc + (long)(kt + 1) * 64);
    asm volatile("s_waitcnt lgkmcnt(0)" ::: "memory");   // reads retired
    BARRIER();                                           // ...block-wide
    if (p2) STGA2(d, Asrc + (long)(kt + 2) * 64);        // A[d] slot now safe

    __builtin_amdgcn_s_setprio(1);
#pragma unroll
    for (int f = 0; f < 4; ++f)
#pragma unroll
      for (int g = 0; g < 4; ++g) {
        f4v t = acc[f][g];
        t = __builtin_amdgcn_mfma_f32_16x16x32_bf16(a[f][0], b[g][0], t, 0, 0, 0);
        t = __builtin_amdgcn_mfma_f32_16x16x32_bf16(a[f][1], b[g][1], t, 0, 0, 0);
        acc[f][g] = t;
      }
    __builtin_amdgcn_s_setprio(0);

    if (p2)      asm volatile("s_waitcnt vmcnt(4)" ::: "memory");
    else if (p1) asm volatile("s_waitcnt vmcnt(0)" ::: "memory");
    else         asm volatile("s_waitcnt vmcnt(0)" ::: "memory");
    BARRIER();
  }

  // epilogue: f32 writes to d_out
#pragma unroll
  for (int f = 0; f < 4; ++f) {
    long row = m0 + wm * 64 + f * 16 + lg * 4;
#pragma unroll
    for (int g = 0; g < 4; ++g) {
      long col = n0 + wn * 64 + g * 16 + lr;
      f4v v = acc[f][g];
#pragma unroll
      for (int r = 0; r < 4; ++r) C[(row + r) * ldc + col] = v[r];
    }
  }
#undef STGA2
#undef STGB2
}

// ---------------------------------------------------------------------------
// Per-head RMSNorm (D=128) + RoPE for K HEADS ONLY, in-place, vectorized.
// ---------------------------------------------------------------------------
__global__ __launch_bounds__(256) void rms_rope_k(us* __restrict__ qkv,
                                                  const float* __restrict__ fc,
                                                  const float* __restrict__ kw) {
  int idx = blockIdx.x * 4 + (threadIdx.x >> 6);
  int lane = threadIdx.x & 63;
  int head = idx & 7;                  // 8 K heads
  int row = idx >> 3;                  // b*1024 + s
  int s = row & 1023;
  us* p = qkv + (long)row * 6144 + 4096 + head * 128;

  unsigned v = ((const unsigned*)p)[lane];
  float x0 = b2f((us)(v & 0xffff)), x1 = b2f((us)(v >> 16));
  float ss = x0 * x0 + x1 * x1;
#pragma unroll
  for (int off = 32; off; off >>= 1) ss += __shfl_xor(ss, off);
  float r = rsqrtf(ss * (1.0f / 128.0f) + 1e-6f);
  float2v wv = ((const float2v*)kw)[lane];
  float y0 = x0 * r * wv[0], y1 = x1 * r * wv[1];
  float py0 = __shfl(y0, lane ^ 32);
  float py1 = __shfl(y1, lane ^ 32);
  float2v cv = ((const float2v*)(fc + (long)s * 128))[lane];
  const float* sbase = (lane < 32) ? (fc + 2 * 1024 * 128) : (fc + 1024 * 128);
  float2v sv = ((const float2v*)(sbase + (long)s * 128))[lane];
  float e0 = y0 * cv[0] + py0 * sv[0];
  float e1 = y1 * cv[1] + py1 * sv[1];
  ((unsigned*)p)[lane] = (unsigned)f2b(e0) | ((unsigned)f2b(e1) << 16);
}

// ---------------------------------------------------------------------------
// Flash attention (no mask), GQA 4:1. Block = 4 waves = 64 q-rows; 64-key
// tiles. Q RMSNorm+RoPE fused in the prologue.
// ---------------------------------------------------------------------------
__global__ __launch_bounds__(256) void attn_k(const us* __restrict__ qkv,
                                              us* __restrict__ ao,
                                              const float* __restrict__ fc,
                                              const float* __restrict__ qw) {
  __shared__ us Kt[64 * 128];   // [key][d], rows 256B, XOR-swizzled
  __shared__ us Vt[128 * 72];   // [d][key], padded rows (144B)
  __shared__ us Pl[4 * 1024];   // per-wave 16x64 P, XOR-swizzled

  const int bid = blockIdx.x;
  const int qt = bid & 15;
  const int h = (bid >> 4) & 31;
  const int b = bid >> 9;
  const int kvh = h >> 2;
  const int tid = threadIdx.x, lane = tid & 63, w = tid >> 6;
  const int lr = lane & 15, lg = lane >> 4;

  // ---- Q prologue: load raw Q frags, apply RMSNorm + RoPE in-register ----
  const int srow = qt * 64 + w * 16 + lr;
  const us* Qb = qkv + (long)(b * 1024 + srow) * 6144 + h * 128;
  s8v qr[4];
#pragma unroll
  for (int ks = 0; ks < 4; ++ks) qr[ks] = *(const s8v*)(Qb + ks * 32 + lg * 8);

  float ssq = 0.f;
#pragma unroll
  for (int ks = 0; ks < 4; ++ks)
#pragma unroll
    for (int j = 0; j < 8; ++j) {
      float x = b2f((us)qr[ks][j]);
      ssq += x * x;
    }
  ssq += __shfl_xor(ssq, 16);
  ssq += __shfl_xor(ssq, 32);
  const float rr = rsqrtf(ssq * (1.0f / 128.0f) + 1e-6f);

  const float* cosp = fc + (long)srow * 128;
  const float* sinp = fc + 1024 * 128 + (long)srow * 128;
  s8v qf[4];
#pragma unroll
  for (int ks = 0; ks < 4; ++ks) {
    const int d0 = ks * 32 + lg * 8;
    const int dp = d0 ^ 64;
    const float sgn = (ks < 2) ? -1.f : 1.f;
#pragma unroll
    for (int j = 0; j < 8; ++j) {
      float y  = b2f((us)qr[ks][j])     * rr * qw[d0 + j];
      float yp = b2f((us)qr[ks ^ 2][j]) * rr * qw[dp + j];
      float e = y * cosp[d0 + j] + yp * sgn * sinp[d0 + j];
      qf[ks][j] = (short)f2b(e);
    }
  }

  f4v o[8];
#pragma unroll
  for (int n = 0; n < 8; ++n) o[n] = (f4v){0.f, 0.f, 0.f, 0.f};
  float m[4], l[4];
#pragma unroll
  for (int r = 0; r < 4; ++r) { m[r] = -1e30f; l[r] = 0.f; }

  const float SL = 0.08838834764831845f * 1.4426950408889634f;  // D^-1/2 * log2e
  const long krow = (long)b * 1024 * 6144 + 4096 + kvh * 128;
  const long vrow = (long)b * 1024 * 6144 + 5120 + kvh * 128;

  for (int kt = 0; kt < 16; ++kt) {
    __syncthreads();
#pragma unroll
    for (int t = 0; t < 4; ++t) {
      int c = t * 256 + tid;
      int row = c >> 4;
      int sc = (c & 15) ^ (row & 7);
      gload16(qkv + krow + (long)(kt * 64 + row) * 6144 + sc * 8, &Kt[c * 8]);
    }
#pragma unroll
    for (int t = 0; t < 2; ++t) {
      int c = t * 256 + tid;
      int kp = c & 31;
      int d0 = (c >> 5) * 8;
      const us* vsrc = qkv + vrow + (long)(kt * 64) * 6144 + d0;
      s8v va = *(const s8v*)(vsrc + (long)(2 * kp) * 6144);
      s8v vb = *(const s8v*)(vsrc + (long)(2 * kp + 1) * 6144);
#pragma unroll
      for (int i = 0; i < 8; ++i) {
        unsigned pk = (unsigned)(us)va[i] | ((unsigned)(us)vb[i] << 16);
        *(unsigned*)&Vt[(d0 + i) * 72 + 2 * kp] = pk;
      }
    }
    __syncthreads();

    f4v sacc[4];
#pragma unroll
    for (int j = 0; j < 4; ++j) sacc[j] = (f4v){0.f, 0.f, 0.f, 0.f};
    __builtin_amdgcn_s_setprio(1);
#pragma unroll
    for (int ks = 0; ks < 4; ++ks) {
#pragma unroll
      for (int j = 0; j < 4; ++j) {
        int key = j * 16 + lr;
        s8v kf = *(const s8v*)&Kt[key * 128 + (((ks * 64 + lg * 16) ^ ((key & 7) << 4)) >> 1)];
        sacc[j] = __builtin_amdgcn_mfma_f32_16x16x32_bf16(qf[ks], kf, sacc[j], 0, 0, 0);
      }
    }
    __builtin_amdgcn_s_setprio(0);

    float sm[4];
#pragma unroll
    for (int r = 0; r < 4; ++r)
      sm[r] = fmaxf(fmaxf(sacc[0][r], sacc[1][r]), fmaxf(sacc[2][r], sacc[3][r]));
#pragma unroll
    for (int off = 1; off < 16; off <<= 1)
#pragma unroll
      for (int r = 0; r < 4; ++r) sm[r] = fmaxf(sm[r], __shfl_xor(sm[r], off));
    float alpha[4];
#pragma unroll
    for (int r = 0; r < 4; ++r) {
      float nm = fmaxf(m[r], sm[r] * SL);
      alpha[r] = exp2f(m[r] - nm);
      m[r] = nm;
      l[r] *= alpha[r];
    }
#pragma unroll
    for (int n = 0; n < 8; ++n)
#pragma unroll
      for (int r = 0; r < 4; ++r) o[n][r] *= alpha[r];

    us* pw = Pl + w * 1024;
#pragma unroll
    for (int j = 0; j < 4; ++j)
#pragma unroll
      for (int r = 0; r < 4; ++r) {
        float p = exp2f(sacc[j][r] * SL - m[r]);
        l[r] += p;
        int prow = lg * 4 + r, pcol = j * 16 + lr;
        pw[(prow * 128 + ((pcol * 2) ^ ((prow & 7) << 4))) >> 1] = f2b(p);
      }

    __builtin_amdgcn_s_setprio(1);
#pragma unroll
    for (int ks = 0; ks < 2; ++ks) {
      int bo = ks * 64 + lg * 16;
      s8v pf = *(const s8v*)&Pl[w * 1024 + ((lr * 128 + (bo ^ ((lr & 7) << 4))) >> 1)];
#pragma unroll
      for (int n = 0; n < 8; ++n) {
        s8v vf = *(const s8v*)&Vt[(n * 16 + lr) * 72 + ks * 32 + lg * 8];
        o[n] = __builtin_amdgcn_mfma_f32_16x16x32_bf16(pf, vf, o[n], 0, 0, 0);
      }
    }
    __builtin_amdgcn_s_setprio(0);
  }

#pragma unroll
  for (int off = 1; off < 16; off <<= 1)
#pragma unroll
    for (int r = 0; r < 4; ++r) l[r] += __shfl_xor(l[r], off);
  float inv[4];
#pragma unroll
  for (int r = 0; r < 4; ++r) inv[r] = 1.f / l[r];
  const long ob = (long)(b * 1024 + qt * 64 + w * 16) * 4096 + h * 128;
#pragma unroll
  for (int n = 0; n < 8; ++n)
#pragma unroll
    for (int r = 0; r < 4; ++r)
      ao[ob + (long)(lg * 4 + r) * 4096 + n * 16 + lr] = f2b(o[n][r] * inv[r]);
}

// ---------------------------------------------------------------------------
// Launch
// ---------------------------------------------------------------------------
extern "C" void kernel_launch(void* const* d_in, const int* in_sizes, int n_in,
                              void* d_out, int out_size, void* d_ws, size_t ws_size,
                              hipStream_t stream) {
  const float* hidden = (const float*)d_in[0];
  const float* fc     = (const float*)d_in[1];
  const float* Wq     = (const float*)d_in[2];
  const float* Wk     = (const float*)d_in[3];
  const float* Wv     = (const float*)d_in[4];
  const float* Wo     = (const float*)d_in[5];
  const float* qw     = (const float*)d_in[6];
  const float* kw     = (const float*)d_in[7];

  us* hb  = (us*)d_ws;                          // [2048][4096] bf16
  us* wb  = hb + (long)2048 * 4096;             // [10240][4096] bf16 (Wq|Wk|Wv|Wo)
  us* wbo = wb + (long)6144 * 4096;             // Wo bf16 [4096][4096]
  us* qkv = wbo + (long)4096 * 4096;            // [2048][6144] bf16
  us* ao  = qkv + (long)2048 * 6144;            // [2048][4096] bf16

  // convert hidden|Wq|Wk|Wv -> contiguous bf16 at hb (Wo converted in-gemm)
  cvt_all_k<<<16384, 256, 0, stream>>>(hidden, Wq, Wk, Wv, hb);

  // fused QKV projection (192 gemm blocks) + Wo convert (64 tail blocks)
  gemm8p<128, false, true><<<256, 512, 0, stream>>>(
      hb, wb, qkv, 4096, 64, 6144, 4, 6, 4, 192, Wo, wbo);

  // K-head RMSNorm + RoPE in place (Q handled inside attn)
  rms_rope_k<<<4096, 256, 0, stream>>>(qkv, fc, kw);

  // flash attention (Q rms+rope fused) -> bf16 [2048][4096]
  attn_k<<<1024, 256, 0, stream>>>(qkv, ao, fc, qw);

  // output projection: gemm2p, 256 blocks full chip, 1 barrier-pair/K-tile
  gemm2p<<<256, 512, 0, stream>>>(ao, wbo, (float*)d_out);
}

// Round 10
// 316.125 us; speedup vs baseline: 1.8404x; 1.0216x over previous
//
#include <hip/hip_runtime.h>

// ---------------------------------------------------------------------------
// Qwen3-style attention block on MI355X (gfx950), bf16 MFMA pipeline.
// B=2, S=1024, HID=4096, H=32, KV=8, D=128.
// Stages: cvt(h,Wq,Wk,Wv) -> QKV GEMM (+Wo-cvt tail) -> K-RMSNorm+RoPE
//         -> flash attn (Q-RMSNorm+RoPE fused) -> out GEMM (gemm2p128).
// gemm2p128 (new): tile 128x128, 4 waves, BK=64, 64KiB LDS -> 2 blocks/CU
// (512-block grid): two independent barrier domains per CU overlap, hiding
// barrier/LDS drains under the other block's MFMA. 1 barrier pair/K-tile,
// counted vmcnt(4), chunk-XOR swizzle, lgkm(0)-pre-barrier WAR discipline.
// ---------------------------------------------------------------------------

typedef __attribute__((ext_vector_type(8))) short s8v;            // 8 bf16 (4 VGPR)
typedef __attribute__((ext_vector_type(4))) float f4v;
typedef __attribute__((ext_vector_type(8))) unsigned short u8v;
typedef __attribute__((ext_vector_type(4))) float float4v;
typedef __attribute__((ext_vector_type(2))) float float2v;
typedef unsigned short us;

#define SB() __builtin_amdgcn_sched_barrier(0)

__device__ __forceinline__ void BARRIER() {
  asm volatile("" ::: "memory");
  __builtin_amdgcn_s_barrier();
  asm volatile("" ::: "memory");
}

__device__ __forceinline__ us f2b(float f) {
  unsigned u = __builtin_bit_cast(unsigned, f);
  u += 0x7fffu + ((u >> 16) & 1u);            // round-to-nearest-even
  return (us)(u >> 16);
}
__device__ __forceinline__ float b2f(us h) {
  return __builtin_bit_cast(float, (unsigned)h << 16);
}

__device__ __forceinline__ void gload16(const void* g, void* l) {
  __builtin_amdgcn_global_load_lds(
      (const __attribute__((address_space(1))) unsigned int*)g,
      (__attribute__((address_space(3))) unsigned int*)l, 16, 0, 0);
}

// ---------------------------------------------------------------------------
// Fused f32 -> bf16 convert: hidden|Wq|Wk|Wv, contiguous bf16 destination.
// ---------------------------------------------------------------------------
__global__ __launch_bounds__(256) void cvt_all_k(const float* __restrict__ h,
                                                 const float* __restrict__ wq,
                                                 const float* __restrict__ wk,
                                                 const float* __restrict__ wv,
                                                 us* __restrict__ dst) {
  long blk = blockIdx.x;
  const float* src;
  long off;
  if (blk < 4096)        { src = h;  off = 0; }
  else if (blk < 12288)  { src = wq; off = 4096; }
  else if (blk < 14336)  { src = wk; off = 12288; }
  else                   { src = wv; off = 14336; }
  long i = (blk - off) * 2048 + (long)threadIdx.x * 8;
  long o = blk * 2048 + (long)threadIdx.x * 8;
  float4v a = *(const float4v*)(src + i);
  float4v b = *(const float4v*)(src + i + 4);
  u8v v;
  v[0] = f2b(a[0]); v[1] = f2b(a[1]); v[2] = f2b(a[2]); v[3] = f2b(a[3]);
  v[4] = f2b(b[0]); v[5] = f2b(b[1]); v[6] = f2b(b[2]); v[7] = f2b(b[3]);
  *(u8v*)(dst + o) = v;
}

// ---------------------------------------------------------------------------
// m201-style 8-phase bf16 GEMM (QKV): C[M,N] = A[M,K] * W[N,K]^T
// (unchanged round-8/9 core: 256x256 tile, counted vmcnt, chunk-XOR swizzle)
// ---------------------------------------------------------------------------
template <int AH, bool F32OUT, bool CVTTAIL>
__global__ __launch_bounds__(512, 2) void gemm8p(const us* __restrict__ A,
                                                 const us* __restrict__ W,
                                                 void* __restrict__ Cv,
                                                 int K, int nkt, int ldc,
                                                 int cm, int cn, int ncn,
                                                 int nGemm,
                                                 const float* __restrict__ csrc,
                                                 us* __restrict__ cdst) {
  if constexpr (CVTTAIL) {
    if ((int)blockIdx.x >= nGemm) {
      long c = (long)((int)blockIdx.x - nGemm) * 512 + threadIdx.x;
      for (; c < 2097152; c += 64 * 512) {      // 16,777,216 elems / 8
        long i = c * 8;
        float4v x = *(const float4v*)(csrc + i);
        float4v y = *(const float4v*)(csrc + i + 4);
        u8v v;
        v[0] = f2b(x[0]); v[1] = f2b(x[1]); v[2] = f2b(x[2]); v[3] = f2b(x[3]);
        v[4] = f2b(y[0]); v[5] = f2b(y[1]); v[6] = f2b(y[2]); v[7] = f2b(y[3]);
        *(u8v*)(cdst + i) = v;
      }
      return;
    }
  }

  constexpr int FR = AH / 32;
  constexpr int LA = AH / 64;
  constexpr int VM = 2 * LA + 2;

  __shared__ __align__(16) us Ah[2][2][AH * 64];
  __shared__ __align__(16) us Bh[2][2][128 * 64];
  const int tid = threadIdx.x, lane = tid & 63, w = tid >> 6;
  const int wr = w >> 2, wc = w & 3;
  const int lr = lane & 15, lg = lane >> 4;

  const int xcd = (int)blockIdx.x & 7;
  const int i2 = (int)blockIdx.x >> 3;
  const int im = i2 % cm, itn = i2 / cm;
  const long m0 = (long)((xcd / ncn) * cm + im) * (2 * AH);
  const long n0 = (long)((xcd % ncn) * cn + itn) * 256;

  const int rA0 = tid >> 3;
  const int sc0 = ((tid & 7) ^ (rA0 & 7)) << 3;

#define STGH(dst, src, LOADS)                                           \
  do {                                                                  \
    const us* _s = (src);                                               \
    us* _d = (dst);                                                     \
    _Pragma("unroll") for (int l = 0; l < (LOADS); ++l)                 \
      gload16(_s + (long)(rA0 + l * 64) * K + sc0, _d + (l * 512 + tid) * 8); \
  } while (0)

  const us* Asrc = A + m0 * K;
  const us* Bsrc = W + n0 * K;
  const long hKA = (long)AH * K;
  const long hKB = (long)128 * K;

  const int ra = wr * (AH / 2) + lr, rb = wc * 32 + lr;
  const int offA0 = ra * 64 + ((lg ^ (ra & 7)) << 3);
  const int offA1 = ra * 64 + (((4 + lg) ^ (ra & 7)) << 3);
  const int offB0 = rb * 64 + ((lg ^ (rb & 7)) << 3);
  const int offB1 = rb * 64 + (((4 + lg) ^ (rb & 7)) << 3);

  f4v acc[2 * FR][4];
#pragma unroll
  for (int i = 0; i < 2 * FR; ++i)
#pragma unroll
    for (int j = 0; j < 4; ++j) acc[i][j] = (f4v){0.f, 0.f, 0.f, 0.f};

  const int nk = nkt;

  STGH(Ah[0][0], Asrc, LA);
  STGH(Bh[0][0], Bsrc, 2);
  STGH(Bh[0][1], Bsrc + hKB, 2);
  STGH(Ah[0][1], Asrc + hKA, LA);
  STGH(Ah[1][0], Asrc + 64, LA);
  STGH(Bh[1][1], Bsrc + hKB + 64, 2);
  STGH(Ah[1][1], Asrc + hKA + 64, LA);
  asm volatile("s_waitcnt vmcnt(%0)" :: "i"(VM) : "memory");
  BARRIER();

  s8v a[FR][2], b0[2][2], b1[2][2];

#define RD_A(H)                                                         \
  _Pragma("unroll") for (int f = 0; f < FR; ++f) {                      \
    a[f][0] = *(const s8v*)(&Ah[d][H][offA0 + f * 1024]);               \
    a[f][1] = *(const s8v*)(&Ah[d][H][offA1 + f * 1024]);               \
  }
#define RD_B(BB, H)                                                     \
  _Pragma("unroll") for (int g = 0; g < 2; ++g) {                       \
    BB[g][0] = *(const s8v*)(&Bh[d][H][offB0 + g * 1024]);              \
    BB[g][1] = *(const s8v*)(&Bh[d][H][offB1 + g * 1024]);              \
  }
#define QUAD(QM, QN, BB)                                                \
  __builtin_amdgcn_s_setprio(1);                                        \
  _Pragma("unroll") for (int f = 0; f < FR; ++f)                        \
  _Pragma("unroll") for (int g = 0; g < 2; ++g) {                       \
    f4v t = acc[QM * FR + f][QN * 2 + g];                               \
    t = __builtin_amdgcn_mfma_f32_16x16x32_bf16(a[f][0], BB[g][0], t, 0, 0, 0); \
    t = __builtin_amdgcn_mfma_f32_16x16x32_bf16(a[f][1], BB[g][1], t, 0, 0, 0); \
    acc[QM * FR + f][QN * 2 + g] = t;                                   \
  }                                                                     \
  __builtin_amdgcn_s_setprio(0);
#define PREMFMA()                                                       \
  BARRIER();                                                            \
  asm volatile("s_waitcnt lgkmcnt(0)" ::: "memory");                    \
  SB();

  for (int kt = 0; kt < nk; ++kt) {
    const int d = kt & 1;
    const long kb2 = (long)(kt + 2) * 64;
    const bool p1 = (kt + 1 < nk), p2 = (kt + 2 < nk);

    RD_A(0)
    RD_B(b0, 0)
    if (p1) STGH(Bh[d ^ 1][0], Bsrc + (long)(kt + 1) * 64, 2);
    PREMFMA()
    QUAD(0, 0, b0)
    BARRIER();

    RD_B(b1, 1)
    if (p2) STGH(Ah[d][0], Asrc + kb2, LA);
    PREMFMA()
    QUAD(0, 1, b1)
    BARRIER();

    RD_A(1)
    if (p2) STGH(Bh[d][1], Bsrc + hKB + kb2, 2);
    PREMFMA()
    QUAD(1, 1, b1)
    BARRIER();

    if (p2) STGH(Ah[d][1], Asrc + hKA + kb2, LA);
    PREMFMA()
    QUAD(1, 0, b0)
    if (p2) asm volatile("s_waitcnt vmcnt(%0)" :: "i"(VM) : "memory");
    else    asm volatile("s_waitcnt vmcnt(0)" ::: "memory");
    BARRIER();
  }

#pragma unroll
  for (int qm = 0; qm < 2; ++qm)
#pragma unroll
    for (int f = 0; f < FR; ++f) {
      long row = m0 + qm * AH + wr * (AH / 2) + f * 16 + lg * 4;
#pragma unroll
      for (int qn = 0; qn < 2; ++qn)
#pragma unroll
        for (int g = 0; g < 2; ++g) {
          long col = n0 + qn * 128 + wc * 32 + g * 16 + lr;
          f4v v = acc[qm * FR + f][qn * 2 + g];
          if constexpr (F32OUT) {
            float* C = (float*)Cv;
#pragma unroll
            for (int r = 0; r < 4; ++r) C[(row + r) * ldc + col] = v[r];
          } else {
            us* C = (us*)Cv;
#pragma unroll
            for (int r = 0; r < 4; ++r) C[(row + r) * ldc + col] = f2b(v[r]);
          }
        }
    }
#undef STGH
#undef RD_A
#undef RD_B
#undef QUAD
#undef PREMFMA
}

// ---------------------------------------------------------------------------
// gemm2p128 (out-proj): C[2048,4096] f32 = A[2048,K]bf16 * W[4096,K]^T bf16
// Tile 128x128, BK=64, 256 threads = 4 waves (2M x 2N), wave = 64x64.
// LDS: Ab[2][128*64] + Bb[2][128*64] = 64 KiB -> 2 blocks/CU (512 blocks).
// Per K-tile (ONE barrier pair):
//   {16 ds_read; stage B(kt+1)->B[d^1]; lgkm(0); BARRIER;
//    stage A(kt+2)->A[d]; 32 MFMA (setprio); vmcnt(4); BARRIER}
// vmcnt(4): outstanding = A(kt+1)4 + B(kt+1)4 + A(kt+2)4 = 12 -> drain 8
// oldest (tile kt+1 fully landed), keep A(kt+2) flying.
// Grid 512 = 16M x 32N; XCD owns 16M x 4N (M-fastest).
// ---------------------------------------------------------------------------
__global__ __launch_bounds__(256, 2) void gemm2p128(const us* __restrict__ A,
                                                    const us* __restrict__ W,
                                                    float* __restrict__ C) {
  constexpr int K = 4096, nk = 64, ldc = 4096;
  __shared__ __align__(16) us Ab[2][128 * 64];
  __shared__ __align__(16) us Bb[2][128 * 64];
  const int tid = threadIdx.x, lane = tid & 63, w = tid >> 6;
  const int wm = w & 1, wn = w >> 1;
  const int lr = lane & 15, lg = lane >> 4;

  const int xcd = (int)blockIdx.x & 7;
  const int i2 = (int)blockIdx.x >> 3;             // 0..63
  const long m0 = (long)(i2 & 15) * 128;
  const long n0 = (long)(xcd * 4 + (i2 >> 4)) * 128;

  const int rA0 = tid >> 3;                        // rows rA0 + l*32
  const int sc0 = ((tid & 7) ^ (rA0 & 7)) << 3;    // (row&7) invariant in l

  const us* Asrc = A + m0 * K;
  const us* Bsrc = W + n0 * K;

#define STG1(Sb, buf, src)                                               \
  do {                                                                   \
    const us* _s = (src);                                                \
    _Pragma("unroll") for (int l = 0; l < 4; ++l)                        \
      gload16(_s + (long)(rA0 + l * 32) * K + sc0,                       \
              &Sb[buf][(l * 256 + tid) * 8]);                            \
  } while (0)

  const int ra = wm * 64 + lr;
  const int rb = wn * 64 + lr;
  const int offA0 = ra * 64 + ((lg ^ (ra & 7)) << 3);
  const int offA1 = ra * 64 + (((4 + lg) ^ (ra & 7)) << 3);
  const int offB0 = rb * 64 + ((lg ^ (rb & 7)) << 3);
  const int offB1 = rb * 64 + (((4 + lg) ^ (rb & 7)) << 3);

  f4v acc[4][4];
#pragma unroll
  for (int f = 0; f < 4; ++f)
#pragma unroll
    for (int g = 0; g < 4; ++g) acc[f][g] = (f4v){0.f, 0.f, 0.f, 0.f};

  // prologue: A(0), B(0), A(1); keep A(1) in flight (vmcnt(4))
  STG1(Ab, 0, Asrc);
  STG1(Bb, 0, Bsrc);
  STG1(Ab, 1, Asrc + 64);
  asm volatile("s_waitcnt vmcnt(4)" ::: "memory");
  BARRIER();

  for (int kt = 0; kt < nk; ++kt) {
    const int d = kt & 1;
    const bool p1 = (kt + 1 < nk), p2 = (kt + 2 < nk);

    s8v a[4][2], b[4][2];
#pragma unroll
    for (int f = 0; f < 4; ++f) {
      a[f][0] = *(const s8v*)(&Ab[d][offA0 + f * 1024]);
      a[f][1] = *(const s8v*)(&Ab[d][offA1 + f * 1024]);
    }
#pragma unroll
    for (int g = 0; g < 4; ++g) {
      b[g][0] = *(const s8v*)(&Bb[d][offB0 + g * 1024]);
      b[g][1] = *(const s8v*)(&Bb[d][offB1 + g * 1024]);
    }
    if (p1) STG1(Bb, d ^ 1, Bsrc + (long)(kt + 1) * 64);
    asm volatile("s_waitcnt lgkmcnt(0)" ::: "memory");   // reads retired
    BARRIER();
    if (p2) STG1(Ab, d, Asrc + (long)(kt + 2) * 64);     // A[d] slot WAR-safe

    __builtin_amdgcn_s_setprio(1);
#pragma unroll
    for (int f = 0; f < 4; ++f)
#pragma unroll
      for (int g = 0; g < 4; ++g) {
        f4v t = acc[f][g];
        t = __builtin_amdgcn_mfma_f32_16x16x32_bf16(a[f][0], b[g][0], t, 0, 0, 0);
        t = __builtin_amdgcn_mfma_f32_16x16x32_bf16(a[f][1], b[g][1], t, 0, 0, 0);
        acc[f][g] = t;
      }
    __builtin_amdgcn_s_setprio(0);

    if (p2) asm volatile("s_waitcnt vmcnt(4)" ::: "memory");
    else    asm volatile("s_waitcnt vmcnt(0)" ::: "memory");
    BARRIER();
  }

#pragma unroll
  for (int f = 0; f < 4; ++f) {
    long row = m0 + wm * 64 + f * 16 + lg * 4;
#pragma unroll
    for (int g = 0; g < 4; ++g) {
      long col = n0 + wn * 64 + g * 16 + lr;
      f4v v = acc[f][g];
#pragma unroll
      for (int r = 0; r < 4; ++r) C[(row + r) * ldc + col] = v[r];
    }
  }
#undef STG1
}

// ---------------------------------------------------------------------------
// Per-head RMSNorm (D=128) + RoPE for K HEADS ONLY, in-place, vectorized.
// ---------------------------------------------------------------------------
__global__ __launch_bounds__(256) void rms_rope_k(us* __restrict__ qkv,
                                                  const float* __restrict__ fc,
                                                  const float* __restrict__ kw) {
  int idx = blockIdx.x * 4 + (threadIdx.x >> 6);
  int lane = threadIdx.x & 63;
  int head = idx & 7;                  // 8 K heads
  int row = idx >> 3;                  // b*1024 + s
  int s = row & 1023;
  us* p = qkv + (long)row * 6144 + 4096 + head * 128;

  unsigned v = ((const unsigned*)p)[lane];
  float x0 = b2f((us)(v & 0xffff)), x1 = b2f((us)(v >> 16));
  float ss = x0 * x0 + x1 * x1;
#pragma unroll
  for (int off = 32; off; off >>= 1) ss += __shfl_xor(ss, off);
  float r = rsqrtf(ss * (1.0f / 128.0f) + 1e-6f);
  float2v wv = ((const float2v*)kw)[lane];
  float y0 = x0 * r * wv[0], y1 = x1 * r * wv[1];
  float py0 = __shfl(y0, lane ^ 32);
  float py1 = __shfl(y1, lane ^ 32);
  float2v cv = ((const float2v*)(fc + (long)s * 128))[lane];
  const float* sbase = (lane < 32) ? (fc + 2 * 1024 * 128) : (fc + 1024 * 128);
  float2v sv = ((const float2v*)(sbase + (long)s * 128))[lane];
  float e0 = y0 * cv[0] + py0 * sv[0];
  float e1 = y1 * cv[1] + py1 * sv[1];
  ((unsigned*)p)[lane] = (unsigned)f2b(e0) | ((unsigned)f2b(e1) << 16);
}

// ---------------------------------------------------------------------------
// Flash attention (no mask), GQA 4:1. Block = 4 waves = 64 q-rows; 64-key
// tiles. Q RMSNorm+RoPE fused in the prologue.
// ---------------------------------------------------------------------------
__global__ __launch_bounds__(256) void attn_k(const us* __restrict__ qkv,
                                              us* __restrict__ ao,
                                              const float* __restrict__ fc,
                                              const float* __restrict__ qw) {
  __shared__ us Kt[64 * 128];   // [key][d], rows 256B, XOR-swizzled
  __shared__ us Vt[128 * 72];   // [d][key], padded rows (144B)
  __shared__ us Pl[4 * 1024];   // per-wave 16x64 P, XOR-swizzled

  const int bid = blockIdx.x;
  const int qt = bid & 15;
  const int h = (bid >> 4) & 31;
  const int b = bid >> 9;
  const int kvh = h >> 2;
  const int tid = threadIdx.x, lane = tid & 63, w = tid >> 6;
  const int lr = lane & 15, lg = lane >> 4;

  // ---- Q prologue: load raw Q frags, apply RMSNorm + RoPE in-register ----
  const int srow = qt * 64 + w * 16 + lr;
  const us* Qb = qkv + (long)(b * 1024 + srow) * 6144 + h * 128;
  s8v qr[4];
#pragma unroll
  for (int ks = 0; ks < 4; ++ks) qr[ks] = *(const s8v*)(Qb + ks * 32 + lg * 8);

  float ssq = 0.f;
#pragma unroll
  for (int ks = 0; ks < 4; ++ks)
#pragma unroll
    for (int j = 0; j < 8; ++j) {
      float x = b2f((us)qr[ks][j]);
      ssq += x * x;
    }
  ssq += __shfl_xor(ssq, 16);
  ssq += __shfl_xor(ssq, 32);
  const float rr = rsqrtf(ssq * (1.0f / 128.0f) + 1e-6f);

  const float* cosp = fc + (long)srow * 128;
  const float* sinp = fc + 1024 * 128 + (long)srow * 128;
  s8v qf[4];
#pragma unroll
  for (int ks = 0; ks < 4; ++ks) {
    const int d0 = ks * 32 + lg * 8;
    const int dp = d0 ^ 64;
    const float sgn = (ks < 2) ? -1.f : 1.f;
#pragma unroll
    for (int j = 0; j < 8; ++j) {
      float y  = b2f((us)qr[ks][j])     * rr * qw[d0 + j];
      float yp = b2f((us)qr[ks ^ 2][j]) * rr * qw[dp + j];
      float e = y * cosp[d0 + j] + yp * sgn * sinp[d0 + j];
      qf[ks][j] = (short)f2b(e);
    }
  }

  f4v o[8];
#pragma unroll
  for (int n = 0; n < 8; ++n) o[n] = (f4v){0.f, 0.f, 0.f, 0.f};
  float m[4], l[4];
#pragma unroll
  for (int r = 0; r < 4; ++r) { m[r] = -1e30f; l[r] = 0.f; }

  const float SL = 0.08838834764831845f * 1.4426950408889634f;  // D^-1/2 * log2e
  const long krow = (long)b * 1024 * 6144 + 4096 + kvh * 128;
  const long vrow = (long)b * 1024 * 6144 + 5120 + kvh * 128;

  for (int kt = 0; kt < 16; ++kt) {
    __syncthreads();
#pragma unroll
    for (int t = 0; t < 4; ++t) {
      int c = t * 256 + tid;
      int row = c >> 4;
      int sc = (c & 15) ^ (row & 7);
      gload16(qkv + krow + (long)(kt * 64 + row) * 6144 + sc * 8, &Kt[c * 8]);
    }
#pragma unroll
    for (int t = 0; t < 2; ++t) {
      int c = t * 256 + tid;
      int kp = c & 31;
      int d0 = (c >> 5) * 8;
      const us* vsrc = qkv + vrow + (long)(kt * 64) * 6144 + d0;
      s8v va = *(const s8v*)(vsrc + (long)(2 * kp) * 6144);
      s8v vb = *(const s8v*)(vsrc + (long)(2 * kp + 1) * 6144);
#pragma unroll
      for (int i = 0; i < 8; ++i) {
        unsigned pk = (unsigned)(us)va[i] | ((unsigned)(us)vb[i] << 16);
        *(unsigned*)&Vt[(d0 + i) * 72 + 2 * kp] = pk;
      }
    }
    __syncthreads();

    f4v sacc[4];
#pragma unroll
    for (int j = 0; j < 4; ++j) sacc[j] = (f4v){0.f, 0.f, 0.f, 0.f};
    __builtin_amdgcn_s_setprio(1);
#pragma unroll
    for (int ks = 0; ks < 4; ++ks) {
#pragma unroll
      for (int j = 0; j < 4; ++j) {
        int key = j * 16 + lr;
        s8v kf = *(const s8v*)&Kt[key * 128 + (((ks * 64 + lg * 16) ^ ((key & 7) << 4)) >> 1)];
        sacc[j] = __builtin_amdgcn_mfma_f32_16x16x32_bf16(qf[ks], kf, sacc[j], 0, 0, 0);
      }
    }
    __builtin_amdgcn_s_setprio(0);

    float sm[4];
#pragma unroll
    for (int r = 0; r < 4; ++r)
      sm[r] = fmaxf(fmaxf(sacc[0][r], sacc[1][r]), fmaxf(sacc[2][r], sacc[3][r]));
#pragma unroll
    for (int off = 1; off < 16; off <<= 1)
#pragma unroll
      for (int r = 0; r < 4; ++r) sm[r] = fmaxf(sm[r], __shfl_xor(sm[r], off));
    float alpha[4];
#pragma unroll
    for (int r = 0; r < 4; ++r) {
      float nm = fmaxf(m[r], sm[r] * SL);
      alpha[r] = exp2f(m[r] - nm);
      m[r] = nm;
      l[r] *= alpha[r];
    }
#pragma unroll
    for (int n = 0; n < 8; ++n)
#pragma unroll
      for (int r = 0; r < 4; ++r) o[n][r] *= alpha[r];

    us* pw = Pl + w * 1024;
#pragma unroll
    for (int j = 0; j < 4; ++j)
#pragma unroll
      for (int r = 0; r < 4; ++r) {
        float p = exp2f(sacc[j][r] * SL - m[r]);
        l[r] += p;
        int prow = lg * 4 + r, pcol = j * 16 + lr;
        pw[(prow * 128 + ((pcol * 2) ^ ((prow & 7) << 4))) >> 1] = f2b(p);
      }

    __builtin_amdgcn_s_setprio(1);
#pragma unroll
    for (int ks = 0; ks < 2; ++ks) {
      int bo = ks * 64 + lg * 16;
      s8v pf = *(const s8v*)&Pl[w * 1024 + ((lr * 128 + (bo ^ ((lr & 7) << 4))) >> 1)];
#pragma unroll
      for (int n = 0; n < 8; ++n) {
        s8v vf = *(const s8v*)&Vt[(n * 16 + lr) * 72 + ks * 32 + lg * 8];
        o[n] = __builtin_amdgcn_mfma_f32_16x16x32_bf16(pf, vf, o[n], 0, 0, 0);
      }
    }
    __builtin_amdgcn_s_setprio(0);
  }

#pragma unroll
  for (int off = 1; off < 16; off <<= 1)
#pragma unroll
    for (int r = 0; r < 4; ++r) l[r] += __shfl_xor(l[r], off);
  float inv[4];
#pragma unroll
  for (int r = 0; r < 4; ++r) inv[r] = 1.f / l[r];
  const long ob = (long)(b * 1024 + qt * 64 + w * 16) * 4096 + h * 128;
#pragma unroll
  for (int n = 0; n < 8; ++n)
#pragma unroll
    for (int r = 0; r < 4; ++r)
      ao[ob + (long)(lg * 4 + r) * 4096 + n * 16 + lr] = f2b(o[n][r] * inv[r]);
}

// ---------------------------------------------------------------------------
// Launch
// ---------------------------------------------------------------------------
extern "C" void kernel_launch(void* const* d_in, const int* in_sizes, int n_in,
                              void* d_out, int out_size, void* d_ws, size_t ws_size,
                              hipStream_t stream) {
  const float* hidden = (const float*)d_in[0];
  const float* fc     = (const float*)d_in[1];
  const float* Wq     = (const float*)d_in[2];
  const float* Wk     = (const float*)d_in[3];
  const float* Wv     = (const float*)d_in[4];
  const float* Wo     = (const float*)d_in[5];
  const float* qw     = (const float*)d_in[6];
  const float* kw     = (const float*)d_in[7];

  us* hb  = (us*)d_ws;                          // [2048][4096] bf16
  us* wb  = hb + (long)2048 * 4096;             // [10240][4096] bf16 (Wq|Wk|Wv|Wo)
  us* wbo = wb + (long)6144 * 4096;             // Wo bf16 [4096][4096]
  us* qkv = wbo + (long)4096 * 4096;            // [2048][6144] bf16
  us* ao  = qkv + (long)2048 * 6144;            // [2048][4096] bf16

  // convert hidden|Wq|Wk|Wv -> contiguous bf16 at hb (Wo converted in-gemm)
  cvt_all_k<<<16384, 256, 0, stream>>>(hidden, Wq, Wk, Wv, hb);

  // fused QKV projection (192 gemm blocks) + Wo convert (64 tail blocks)
  gemm8p<128, false, true><<<256, 512, 0, stream>>>(
      hb, wb, qkv, 4096, 64, 6144, 4, 6, 4, 192, Wo, wbo);

  // K-head RMSNorm + RoPE in place (Q handled inside attn)
  rms_rope_k<<<4096, 256, 0, stream>>>(qkv, fc, kw);

  // flash attention (Q rms+rope fused) -> bf16 [2048][4096]
  attn_k<<<1024, 256, 0, stream>>>(qkv, ao, fc, qw);

  // output projection: 128x128 tiles, 512 blocks (2 blocks/CU), 1 pair/K-tile
  gemm2p128<<<512, 256, 0, stream>>>(ao, wbo, (float*)d_out);
}